// Round 5
// baseline (1427.967 us; speedup 1.0000x reference)
//
#include <hip/hip_runtime.h>
#include <hip/hip_bf16.h>

#define N_NODES 100000
#define N_EDGES 640000
#define D_EE 32
#define D_O  128
#define SCAN_CHUNK 1024
#define NB_SCAN ((N_NODES + SCAN_CHUNK - 1) / SCAN_CHUNK)  // 98
#define EPB 128                       // edges per k_edge_mlp block
#define NBLK_E (N_EDGES / EPB)        // 5000

typedef unsigned short u16;
typedef unsigned int u32;

// ---------- helpers ----------
__device__ __forceinline__ float4 fma4(float4 a, float s, float4 b) {
    a.x = fmaf(s, b.x, a.x);
    a.y = fmaf(s, b.y, a.y);
    a.z = fmaf(s, b.z, a.z);
    a.w = fmaf(s, b.w, a.w);
    return a;
}
__device__ __forceinline__ u16 f2bf(float f) {
    u32 b = __float_as_uint(f);
    return (u16)((b + 0x7FFFu + ((b >> 16) & 1u)) >> 16);  // RNE
}
__device__ __forceinline__ float bf2f(u16 u) {
    return __uint_as_float((u32)u << 16);
}

// ---------- K0: fold weights ----------
// A[i][j]=sum_k Wx[i][k]*Wm[k][j]; B[i][j]=sum_k We[i][k]*Wm[128+k][j]
// c[j]=bm[j]+sum_k bx[k]*Wm[k][j]+sum_k be[k]*Wm[128+k][j]
__global__ __launch_bounds__(256) void k_fold(
    const float* __restrict__ Wx, const float* __restrict__ bx,
    const float* __restrict__ We, const float* __restrict__ be,
    const float* __restrict__ Wm, const float* __restrict__ bm,
    float* __restrict__ A, float* __restrict__ B, float* __restrict__ c) {
    int idx = blockIdx.x * 256 + threadIdx.x;
    if (idx < 16384) {
        int i = idx >> 7, j = idx & 127;
        float s = 0.f;
        for (int k = 0; k < 128; ++k) s = fmaf(Wx[i * 128 + k], Wm[k * 128 + j], s);
        A[idx] = s;
    } else if (idx < 16384 + 4096) {
        int t = idx - 16384;
        int i = t >> 7, j = t & 127;
        float s = 0.f;
        for (int k = 0; k < 128; ++k) s = fmaf(We[i * 128 + k], Wm[(128 + k) * 128 + j], s);
        B[t] = s;
    } else if (idx < 16384 + 4096 + 128) {
        int j = idx - 20480;
        float s = bm[j];
        for (int k = 0; k < 128; ++k) s = fmaf(bx[k], Wm[k * 128 + j], s);
        for (int k = 0; k < 128; ++k) s = fmaf(be[k], Wm[(128 + k) * 128 + j], s);
        c[j] = s;
    }
}

// ---------- detect int32 vs int64 edge_index ----------
__global__ void k_detect(const int* __restrict__ ei, int* __restrict__ flag) {
    if (threadIdx.x == 0 && blockIdx.x == 0) {
        int o = 0;
        for (int i = 1; i < 64; i += 2) o |= ei[i];
        flag[0] = (o != 0) ? 1 : 0;  // 1 => int32, 0 => int64
    }
}

// ---------- zero (float4-wide) ----------
__global__ __launch_bounds__(256) void k_zero(float4* __restrict__ p, int n4) {
    int i = blockIdx.x * 256 + threadIdx.x;
    int stride = gridDim.x * 256;
    float4 z = make_float4(0.f, 0.f, 0.f, 0.f);
    for (; i < n4; i += stride) p[i] = z;
}

// ---------- extract indices + histogram of dst ----------
__global__ __launch_bounds__(256) void k_extract_hist(
    const void* __restrict__ ei_raw, const int* __restrict__ flag,
    int* __restrict__ srcA, int* __restrict__ dstA, int* __restrict__ counts) {
    int e = blockIdx.x * 256 + threadIdx.x;
    if (e >= N_EDGES) return;
    int src, dst;
    if (flag[0]) {
        const int* ei32 = (const int*)ei_raw;
        src = ei32[e];
        dst = ei32[N_EDGES + e];
    } else {
        const long long* ei64 = (const long long*)ei_raw;
        src = (int)ei64[e];
        dst = (int)ei64[N_EDGES + e];
    }
    srcA[e] = src;
    dstA[e] = dst;
    atomicAdd(&counts[dst], 1);
}

// ---------- scan A ----------
__global__ __launch_bounds__(256) void k_scan_a(
    const int* __restrict__ counts, int* __restrict__ bsum) {
    __shared__ int L[256];
    int b = blockIdx.x, t = threadIdx.x;
    int base = b * SCAN_CHUNK + t * 4;
    int s = 0;
#pragma unroll
    for (int r = 0; r < 4; ++r) {
        int i = base + r;
        if (i < N_NODES) s += counts[i];
    }
    L[t] = s;
    __syncthreads();
    for (int h = 128; h > 0; h >>= 1) {
        if (t < h) L[t] += L[t + h];
        __syncthreads();
    }
    if (t == 0) bsum[b] = L[0];
}

// ---------- scan B ----------
__global__ void k_scan_b(const int* __restrict__ bsum, int* __restrict__ boff) {
    if (threadIdx.x == 0 && blockIdx.x == 0) {
        int run = 0;
        for (int i = 0; i < NB_SCAN; ++i) { boff[i] = run; run += bsum[i]; }
    }
}

// ---------- scan C ----------
__global__ __launch_bounds__(256) void k_scan_c(
    const int* __restrict__ counts, const int* __restrict__ boff,
    int* __restrict__ offsets) {
    __shared__ int L[256];
    int b = blockIdx.x, t = threadIdx.x;
    int base = b * SCAN_CHUNK + t * 4;
    int c0 = 0, c1 = 0, c2 = 0, c3 = 0;
    if (base + 0 < N_NODES) c0 = counts[base + 0];
    if (base + 1 < N_NODES) c1 = counts[base + 1];
    if (base + 2 < N_NODES) c2 = counts[base + 2];
    if (base + 3 < N_NODES) c3 = counts[base + 3];
    L[t] = c0 + c1 + c2 + c3;
    __syncthreads();
    if (t == 0) {
        int run = 0;
        for (int i = 0; i < 256; ++i) { int tmp = L[i]; L[i] = run; run += tmp; }
    }
    __syncthreads();
    int o = boff[b] + L[t];
    if (base + 0 < N_NODES) offsets[base + 0] = o;
    if (base + 1 < N_NODES) offsets[base + 1] = o + c0;
    if (base + 2 < N_NODES) offsets[base + 2] = o + c0 + c1;
    if (base + 3 < N_NODES) offsets[base + 3] = o + c0 + c1 + c2;
}

// ---------- scatter: perm/src/dst in dst-sorted order ----------
__global__ __launch_bounds__(256) void k_scatter(
    const int* __restrict__ dstA, const int* __restrict__ srcA,
    const int* __restrict__ offsets, int* __restrict__ cursor,
    int* __restrict__ perm, int* __restrict__ src_s, int* __restrict__ dst_s) {
    int e = blockIdx.x * 256 + threadIdx.x;
    if (e >= N_EDGES) return;
    int d = dstA[e];
    int pos = offsets[d] + atomicAdd(&cursor[d], 1);
    perm[pos] = e;
    src_s[pos] = srcA[e];
    dst_s[pos] = d;
}

// ---------- K1: n2 = x @ A + c  -> bf16 [100000,128] ----------
__global__ __launch_bounds__(256) void k_node(
    const float* __restrict__ x, const float* __restrict__ A,
    const float* __restrict__ c, u16* __restrict__ n2b) {
    __shared__ float xs[16 * 128];
    int tid = threadIdx.x;
    int nb = blockIdx.x * 16;
    {
        const float4* xg = (const float4*)(x + (size_t)nb * 128);
        float4* xs4 = (float4*)xs;
        for (int i = tid; i < 512; i += 256) xs4[i] = xg[i];
    }
    __syncthreads();
    int tj = tid & 31, tn = tid >> 5;
    int j0 = tj * 4;
    float4 cc = *(const float4*)(c + j0);
    float4 acc0 = cc, acc1 = cc;
    const float* xr0 = xs + tn * 128;
    const float* xr1 = xs + (tn + 8) * 128;
    const float* Ap = A + j0;
#pragma unroll 4
    for (int k = 0; k < 128; k += 4) {
        float4 a0 = *(const float4*)(Ap + (size_t)(k + 0) * 128);
        float4 a1 = *(const float4*)(Ap + (size_t)(k + 1) * 128);
        float4 a2 = *(const float4*)(Ap + (size_t)(k + 2) * 128);
        float4 a3 = *(const float4*)(Ap + (size_t)(k + 3) * 128);
        float4 xa = *(const float4*)(xr0 + k);
        float4 xb = *(const float4*)(xr1 + k);
        acc0 = fma4(acc0, xa.x, a0); acc1 = fma4(acc1, xb.x, a0);
        acc0 = fma4(acc0, xa.y, a1); acc1 = fma4(acc1, xb.y, a1);
        acc0 = fma4(acc0, xa.z, a2); acc1 = fma4(acc1, xb.z, a2);
        acc0 = fma4(acc0, xa.w, a3); acc1 = fma4(acc1, xb.w, a3);
    }
    ushort4 o0 = make_ushort4(f2bf(acc0.x), f2bf(acc0.y), f2bf(acc0.z), f2bf(acc0.w));
    ushort4 o1 = make_ushort4(f2bf(acc1.x), f2bf(acc1.y), f2bf(acc1.z), f2bf(acc1.w));
    *(ushort4*)(n2b + (size_t)(nb + tn) * 128 + j0) = o0;
    *(ushort4*)(n2b + (size_t)(nb + tn + 8) * 128 + j0) = o1;
}

// ---------- K2: edge MLP + in-block segmented reduce ----------
// Block owns 128 sorted edges. Phase 1: 32 col-quads x 8 edge-slots compute
// msg = leaky(n2[src] + ea[perm]@B) -> LDS bf16 [128][128].
// Phase 2: wave 0 sweeps rows by dst: interior runs -> plain agg store;
// boundary runs (first/last of block) -> unsafeAtomicAdd.
__global__ __launch_bounds__(256, 4) void k_edge_mlp(
    const float* __restrict__ ea, const int* __restrict__ perm,
    const int* __restrict__ src_s, const int* __restrict__ dst_s,
    const float* __restrict__ B, const u16* __restrict__ n2b,
    float* __restrict__ agg) {
    __shared__ u16 msg[EPB][128];
    int tid = threadIdx.x;
    int base = blockIdx.x * EPB;
    int jt = tid & 31, g = tid >> 5;
    int j0 = jt * 4;
    const float* Bp = B + j0;
#pragma unroll 1
    for (int t = 0; t < 8; ++t) {
        int le0 = t * 16 + g, le1 = le0 + 8;
        int p0 = perm[base + le0], p1 = perm[base + le1];
        int s0 = src_s[base + le0], s1 = src_s[base + le1];
        const float* ya_p = ea + (size_t)p0 * 32;
        const float* yb_p = ea + (size_t)p1 * 32;
        float4 acc0 = make_float4(0.f, 0.f, 0.f, 0.f);
        float4 acc1 = make_float4(0.f, 0.f, 0.f, 0.f);
#pragma unroll
        for (int k4 = 0; k4 < 8; ++k4) {
            float4 b0 = *(const float4*)(Bp + (size_t)(k4 * 4 + 0) * 128);
            float4 b1 = *(const float4*)(Bp + (size_t)(k4 * 4 + 1) * 128);
            float4 b2 = *(const float4*)(Bp + (size_t)(k4 * 4 + 2) * 128);
            float4 b3 = *(const float4*)(Bp + (size_t)(k4 * 4 + 3) * 128);
            float4 ya = *(const float4*)(ya_p + k4 * 4);
            float4 yb = *(const float4*)(yb_p + k4 * 4);
            acc0 = fma4(acc0, ya.x, b0); acc1 = fma4(acc1, yb.x, b0);
            acc0 = fma4(acc0, ya.y, b1); acc1 = fma4(acc1, yb.y, b1);
            acc0 = fma4(acc0, ya.z, b2); acc1 = fma4(acc1, yb.z, b2);
            acc0 = fma4(acc0, ya.w, b3); acc1 = fma4(acc1, yb.w, b3);
        }
        ushort4 u0 = *(const ushort4*)(n2b + (size_t)s0 * 128 + j0);
        ushort4 u1 = *(const ushort4*)(n2b + (size_t)s1 * 128 + j0);
        acc0.x += bf2f(u0.x); acc0.y += bf2f(u0.y);
        acc0.z += bf2f(u0.z); acc0.w += bf2f(u0.w);
        acc1.x += bf2f(u1.x); acc1.y += bf2f(u1.y);
        acc1.z += bf2f(u1.z); acc1.w += bf2f(u1.w);
        acc0.x = acc0.x > 0.f ? acc0.x : 0.01f * acc0.x;
        acc0.y = acc0.y > 0.f ? acc0.y : 0.01f * acc0.y;
        acc0.z = acc0.z > 0.f ? acc0.z : 0.01f * acc0.z;
        acc0.w = acc0.w > 0.f ? acc0.w : 0.01f * acc0.w;
        acc1.x = acc1.x > 0.f ? acc1.x : 0.01f * acc1.x;
        acc1.y = acc1.y > 0.f ? acc1.y : 0.01f * acc1.y;
        acc1.z = acc1.z > 0.f ? acc1.z : 0.01f * acc1.z;
        acc1.w = acc1.w > 0.f ? acc1.w : 0.01f * acc1.w;
        ushort4 m0 = make_ushort4(f2bf(acc0.x), f2bf(acc0.y), f2bf(acc0.z), f2bf(acc0.w));
        ushort4 m1 = make_ushort4(f2bf(acc1.x), f2bf(acc1.y), f2bf(acc1.z), f2bf(acc1.w));
        *(ushort4*)(&msg[le0][j0]) = m0;
        *(ushort4*)(&msg[le1][j0]) = m1;
    }
    __syncthreads();
    if (tid < 64) {
        int lane = tid;
        const int col = lane * 2;
        float a0 = 0.f, a1 = 0.f;
        int cur = dst_s[base];
        int rs = 0;
        for (int e = 0; e < EPB; ++e) {
            int d = dst_s[base + e];
            if (d != cur) {
                float* ap = agg + (size_t)cur * 128 + col;
                if (rs > 0) {                       // run strictly inside block
                    *(float2*)ap = make_float2(a0, a1);
                } else {                            // touches block start
                    unsafeAtomicAdd(ap + 0, a0);
                    unsafeAtomicAdd(ap + 1, a1);
                }
                a0 = a1 = 0.f;
                cur = d;
                rs = e;
            }
            u32 w = *(const u32*)(&msg[e][col]);
            a0 += bf2f((u16)(w & 0xffffu));
            a1 += bf2f((u16)(w >> 16));
        }
        float* ap = agg + (size_t)cur * 128 + col;  // touches block end
        unsafeAtomicAdd(ap + 0, a0);
        unsafeAtomicAdd(ap + 1, a1);
    }
}

// ---------- K3: out = sigmoid(agg) * relu(beta) ----------
__global__ __launch_bounds__(256) void k_final(
    const float* __restrict__ agg, const float* __restrict__ beta,
    float4* __restrict__ out) {
    float rb = fmaxf(beta[0], 0.f);
    int i = blockIdx.x * 256 + threadIdx.x;
    int stride = gridDim.x * 256;
    const float4* a4 = (const float4*)agg;
    const int n4 = N_NODES * D_O / 4;
    for (; i < n4; i += stride) {
        float4 v = a4[i];
        float4 r;
        r.x = rb / (1.f + __expf(-v.x));
        r.y = rb / (1.f + __expf(-v.y));
        r.z = rb / (1.f + __expf(-v.z));
        r.w = rb / (1.f + __expf(-v.w));
        out[i] = r;
    }
}

// ---------- launch ----------
extern "C" void kernel_launch(void* const* d_in, const int* in_sizes, int n_in,
                              void* d_out, int out_size, void* d_ws, size_t ws_size,
                              hipStream_t stream) {
    const float* x    = (const float*)d_in[0];
    const float* ea   = (const float*)d_in[1];
    const float* Wx   = (const float*)d_in[2];
    const float* bx   = (const float*)d_in[3];
    const float* We   = (const float*)d_in[4];
    const float* be   = (const float*)d_in[5];
    const float* Wm   = (const float*)d_in[6];
    const float* bm   = (const float*)d_in[7];
    const float* beta = (const float*)d_in[8];
    const void*  ei   = d_in[9];

    // ws layout (byte offsets):
    //   A @0 (65536), B @65536 (16384), c @81920 (512), flag @82432 (64)
    //   srcA @131072, dstA @2691072, counts @5251072, cursor @5651072
    //   bsum @6051072, boff @6051584, offs @6052096
    //   perm @6452096, src_s @9012096, dst_s @11572096 (each 2,560,000)
    //   n2b @14132096 (25,600,000), agg @39732096 (51,200,000) -> 90,932,096
    if (ws_size < (size_t)90932096) return;

    char* ws = (char*)d_ws;
    float* A      = (float*)(ws);
    float* B      = (float*)(ws + 65536);
    float* c      = (float*)(ws + 81920);
    int*   flag   = (int*)(ws + 82432);
    int*   srcA   = (int*)(ws + 131072);
    int*   dstA   = (int*)(ws + 2691072);
    int*   counts = (int*)(ws + 5251072);
    int*   cursor = (int*)(ws + 5651072);
    int*   bsum   = (int*)(ws + 6051072);
    int*   boff   = (int*)(ws + 6051584);
    int*   offs   = (int*)(ws + 6052096);
    int*   perm   = (int*)(ws + 6452096);
    int*   src_s  = (int*)(ws + 9012096);
    int*   dst_s  = (int*)(ws + 11572096);
    u16*   n2b    = (u16*)(ws + 14132096);
    float* agg    = (float*)(ws + 39732096);

    k_fold<<<81, 256, 0, stream>>>(Wx, bx, We, be, Wm, bm, A, B, c);
    k_detect<<<1, 64, 0, stream>>>((const int*)ei, flag);
    k_zero<<<196, 256, 0, stream>>>((float4*)counts, 50000);      // counts+cursor
    k_zero<<<2048, 256, 0, stream>>>((float4*)agg, N_NODES * D_O / 4);
    k_extract_hist<<<2500, 256, 0, stream>>>(ei, flag, srcA, dstA, counts);
    k_scan_a<<<NB_SCAN, 256, 0, stream>>>(counts, bsum);
    k_scan_b<<<1, 64, 0, stream>>>(bsum, boff);
    k_scan_c<<<NB_SCAN, 256, 0, stream>>>(counts, boff, offs);
    k_scatter<<<2500, 256, 0, stream>>>(dstA, srcA, offs, cursor, perm, src_s, dst_s);
    k_node<<<N_NODES / 16, 256, 0, stream>>>(x, A, c, n2b);
    k_edge_mlp<<<NBLK_E, 256, 0, stream>>>(ea, perm, src_s, dst_s, B, n2b, agg);
    k_final<<<2048, 256, 0, stream>>>(agg, beta, (float4*)d_out);
}

// Round 6
// 435.694 us; speedup vs baseline: 3.2775x; 3.2775x over previous
//
#include <hip/hip_runtime.h>
#include <hip/hip_bf16.h>

#define N_NODES 100000
#define N_EDGES 640000
#define D_EE 32
#define D_O  128
#define SCAN_CHUNK 1024
#define NB_SCAN ((N_NODES + SCAN_CHUNK - 1) / SCAN_CHUNK)  // 98
#define EPB 256                       // edges per k_edge_mlp block
#define NBLK_E (N_EDGES / EPB)        // 2500

typedef unsigned short u16;
typedef unsigned int u32;

// ---------- helpers ----------
__device__ __forceinline__ float4 fma4(float4 a, float s, float4 b) {
    a.x = fmaf(s, b.x, a.x);
    a.y = fmaf(s, b.y, a.y);
    a.z = fmaf(s, b.z, a.z);
    a.w = fmaf(s, b.w, a.w);
    return a;
}
__device__ __forceinline__ u16 f2bf(float f) {
    u32 b = __float_as_uint(f);
    return (u16)((b + 0x7FFFu + ((b >> 16) & 1u)) >> 16);  // RNE
}
__device__ __forceinline__ float bf2f(u16 u) {
    return __uint_as_float((u32)u << 16);
}

// ---------- K0: fold weights ----------
// A[i][j]=sum_k Wx[i][k]*Wm[k][j]; B[i][j]=sum_k We[i][k]*Wm[128+k][j]
// c[j]=bm[j]+sum_k bx[k]*Wm[k][j]+sum_k be[k]*Wm[128+k][j]
__global__ __launch_bounds__(256) void k_fold(
    const float* __restrict__ Wx, const float* __restrict__ bx,
    const float* __restrict__ We, const float* __restrict__ be,
    const float* __restrict__ Wm, const float* __restrict__ bm,
    float* __restrict__ A, float* __restrict__ B, float* __restrict__ c) {
    int idx = blockIdx.x * 256 + threadIdx.x;
    if (idx < 16384) {
        int i = idx >> 7, j = idx & 127;
        float s = 0.f;
        for (int k = 0; k < 128; ++k) s = fmaf(Wx[i * 128 + k], Wm[k * 128 + j], s);
        A[idx] = s;
    } else if (idx < 16384 + 4096) {
        int t = idx - 16384;
        int i = t >> 7, j = t & 127;
        float s = 0.f;
        for (int k = 0; k < 128; ++k) s = fmaf(We[i * 128 + k], Wm[(128 + k) * 128 + j], s);
        B[t] = s;
    } else if (idx < 16384 + 4096 + 128) {
        int j = idx - 20480;
        float s = bm[j];
        for (int k = 0; k < 128; ++k) s = fmaf(bx[k], Wm[k * 128 + j], s);
        for (int k = 0; k < 128; ++k) s = fmaf(be[k], Wm[(128 + k) * 128 + j], s);
        c[j] = s;
    }
}

// ---------- detect int32 vs int64 edge_index ----------
__global__ void k_detect(const int* __restrict__ ei, int* __restrict__ flag) {
    if (threadIdx.x == 0 && blockIdx.x == 0) {
        int o = 0;
        for (int i = 1; i < 64; i += 2) o |= ei[i];
        flag[0] = (o != 0) ? 1 : 0;  // 1 => int32, 0 => int64
    }
}

// ---------- zero (float4-wide) ----------
__global__ __launch_bounds__(256) void k_zero(float4* __restrict__ p, int n4) {
    int i = blockIdx.x * 256 + threadIdx.x;
    int stride = gridDim.x * 256;
    float4 z = make_float4(0.f, 0.f, 0.f, 0.f);
    for (; i < n4; i += stride) p[i] = z;
}

// ---------- extract indices + histogram of dst ----------
__global__ __launch_bounds__(256) void k_extract_hist(
    const void* __restrict__ ei_raw, const int* __restrict__ flag,
    int* __restrict__ srcA, int* __restrict__ dstA, int* __restrict__ counts) {
    int e = blockIdx.x * 256 + threadIdx.x;
    if (e >= N_EDGES) return;
    int src, dst;
    if (flag[0]) {
        const int* ei32 = (const int*)ei_raw;
        src = ei32[e];
        dst = ei32[N_EDGES + e];
    } else {
        const long long* ei64 = (const long long*)ei_raw;
        src = (int)ei64[e];
        dst = (int)ei64[N_EDGES + e];
    }
    srcA[e] = src;
    dstA[e] = dst;
    atomicAdd(&counts[dst], 1);
}

// ---------- scan A ----------
__global__ __launch_bounds__(256) void k_scan_a(
    const int* __restrict__ counts, int* __restrict__ bsum) {
    __shared__ int L[256];
    int b = blockIdx.x, t = threadIdx.x;
    int base = b * SCAN_CHUNK + t * 4;
    int s = 0;
#pragma unroll
    for (int r = 0; r < 4; ++r) {
        int i = base + r;
        if (i < N_NODES) s += counts[i];
    }
    L[t] = s;
    __syncthreads();
    for (int h = 128; h > 0; h >>= 1) {
        if (t < h) L[t] += L[t + h];
        __syncthreads();
    }
    if (t == 0) bsum[b] = L[0];
}

// ---------- scan B ----------
__global__ void k_scan_b(const int* __restrict__ bsum, int* __restrict__ boff) {
    if (threadIdx.x == 0 && blockIdx.x == 0) {
        int run = 0;
        for (int i = 0; i < NB_SCAN; ++i) { boff[i] = run; run += bsum[i]; }
    }
}

// ---------- scan C ----------
__global__ __launch_bounds__(256) void k_scan_c(
    const int* __restrict__ counts, const int* __restrict__ boff,
    int* __restrict__ offsets) {
    __shared__ int L[256];
    int b = blockIdx.x, t = threadIdx.x;
    int base = b * SCAN_CHUNK + t * 4;
    int c0 = 0, c1 = 0, c2 = 0, c3 = 0;
    if (base + 0 < N_NODES) c0 = counts[base + 0];
    if (base + 1 < N_NODES) c1 = counts[base + 1];
    if (base + 2 < N_NODES) c2 = counts[base + 2];
    if (base + 3 < N_NODES) c3 = counts[base + 3];
    L[t] = c0 + c1 + c2 + c3;
    __syncthreads();
    if (t == 0) {
        int run = 0;
        for (int i = 0; i < 256; ++i) { int tmp = L[i]; L[i] = run; run += tmp; }
    }
    __syncthreads();
    int o = boff[b] + L[t];
    if (base + 0 < N_NODES) offsets[base + 0] = o;
    if (base + 1 < N_NODES) offsets[base + 1] = o + c0;
    if (base + 2 < N_NODES) offsets[base + 2] = o + c0 + c1;
    if (base + 3 < N_NODES) offsets[base + 3] = o + c0 + c1 + c2;
}

// ---------- scatter: perm/src/dst in dst-sorted order ----------
__global__ __launch_bounds__(256) void k_scatter(
    const int* __restrict__ dstA, const int* __restrict__ srcA,
    const int* __restrict__ offsets, int* __restrict__ cursor,
    int* __restrict__ perm, int* __restrict__ src_s, int* __restrict__ dst_s) {
    int e = blockIdx.x * 256 + threadIdx.x;
    if (e >= N_EDGES) return;
    int d = dstA[e];
    int pos = offsets[d] + atomicAdd(&cursor[d], 1);
    perm[pos] = e;
    src_s[pos] = srcA[e];
    dst_s[pos] = d;
}

// ---------- K1: n2 = x @ A + c  -> bf16 [100000,128] ----------
__global__ __launch_bounds__(256) void k_node(
    const float* __restrict__ x, const float* __restrict__ A,
    const float* __restrict__ c, u16* __restrict__ n2b) {
    __shared__ float xs[16 * 128];
    int tid = threadIdx.x;
    int nb = blockIdx.x * 16;
    {
        const float4* xg = (const float4*)(x + (size_t)nb * 128);
        float4* xs4 = (float4*)xs;
        for (int i = tid; i < 512; i += 256) xs4[i] = xg[i];
    }
    __syncthreads();
    int tj = tid & 31, tn = tid >> 5;
    int j0 = tj * 4;
    float4 cc = *(const float4*)(c + j0);
    float4 acc0 = cc, acc1 = cc;
    const float* xr0 = xs + tn * 128;
    const float* xr1 = xs + (tn + 8) * 128;
    const float* Ap = A + j0;
#pragma unroll 4
    for (int k = 0; k < 128; k += 4) {
        float4 a0 = *(const float4*)(Ap + (size_t)(k + 0) * 128);
        float4 a1 = *(const float4*)(Ap + (size_t)(k + 1) * 128);
        float4 a2 = *(const float4*)(Ap + (size_t)(k + 2) * 128);
        float4 a3 = *(const float4*)(Ap + (size_t)(k + 3) * 128);
        float4 xa = *(const float4*)(xr0 + k);
        float4 xb = *(const float4*)(xr1 + k);
        acc0 = fma4(acc0, xa.x, a0); acc1 = fma4(acc1, xb.x, a0);
        acc0 = fma4(acc0, xa.y, a1); acc1 = fma4(acc1, xb.y, a1);
        acc0 = fma4(acc0, xa.z, a2); acc1 = fma4(acc1, xb.z, a2);
        acc0 = fma4(acc0, xa.w, a3); acc1 = fma4(acc1, xb.w, a3);
    }
    ushort4 o0 = make_ushort4(f2bf(acc0.x), f2bf(acc0.y), f2bf(acc0.z), f2bf(acc0.w));
    ushort4 o1 = make_ushort4(f2bf(acc1.x), f2bf(acc1.y), f2bf(acc1.z), f2bf(acc1.w));
    *(ushort4*)(n2b + (size_t)(nb + tn) * 128 + j0) = o0;
    *(ushort4*)(n2b + (size_t)(nb + tn + 8) * 128 + j0) = o1;
}

// ---------- K2: edge MLP, column-sweep over sorted edges ----------
// Block owns 256 sorted edges. Stage ea[256][32] in LDS (coalesced, once).
// 256 threads = 128 cols x 2 halves; thread owns col c, B[:,c] in 32 VGPRs,
// sweeps its 128 edges in dst-order, f32 run-accumulate in register;
// interior runs -> plain store, half-boundary runs -> atomic.
__global__ __launch_bounds__(256, 4) void k_edge_mlp(
    const float* __restrict__ ea, const int* __restrict__ perm,
    const int* __restrict__ src_s, const int* __restrict__ dst_s,
    const float* __restrict__ B, const u16* __restrict__ n2b,
    float* __restrict__ agg) {
    __shared__ float ea_s[EPB * 33];   // stride 33: staging-write bank spread
    __shared__ int src_l[EPB];
    __shared__ int dst_l[EPB];
    int tid = threadIdx.x;
    int base = blockIdx.x * EPB;
    src_l[tid] = src_s[base + tid];
    dst_l[tid] = dst_s[base + tid];
    {
        int q = tid & 7;               // float4 slot within 32-f row
        int e0 = tid >> 3;             // 0..31
#pragma unroll
        for (int ch = 0; ch < 8; ++ch) {
            int e = e0 + ch * 32;
            int p = perm[base + e];
            float4 v = *(const float4*)(ea + (size_t)p * 32 + q * 4);
            float* w = &ea_s[e * 33 + q * 4];
            w[0] = v.x; w[1] = v.y; w[2] = v.z; w[3] = v.w;
        }
    }
    int c = tid & 127;
    int h = tid >> 7;
    float b[32];
#pragma unroll
    for (int k = 0; k < 32; ++k) b[k] = B[k * 128 + c];
    __syncthreads();

    int ebeg = h * 128, eend = ebeg + 128;
    float acc = 0.f;
    int cur = dst_l[ebeg];
    int nflush = 0;
    u16 nv = n2b[(size_t)src_l[ebeg] * 128 + c];
    for (int e = ebeg; e < eend; ++e) {
        u16 nv_nxt = 0;
        if (e + 1 < eend) nv_nxt = n2b[(size_t)src_l[e + 1] * 128 + c];
        int d = dst_l[e];
        if (d != cur) {
            float* ap = agg + (size_t)cur * 128 + c;
            if (nflush) *ap = acc;
            else unsafeAtomicAdd(ap, acc);
            ++nflush;
            acc = 0.f;
            cur = d;
        }
        const float* er = &ea_s[e * 33];
        float m0 = bf2f(nv), m1 = 0.f, m2 = 0.f, m3 = 0.f;
#pragma unroll
        for (int k = 0; k < 32; k += 4) {
            m0 = fmaf(er[k + 0], b[k + 0], m0);
            m1 = fmaf(er[k + 1], b[k + 1], m1);
            m2 = fmaf(er[k + 2], b[k + 2], m2);
            m3 = fmaf(er[k + 3], b[k + 3], m3);
        }
        float m = (m0 + m1) + (m2 + m3);
        acc += (m > 0.f) ? m : 0.01f * m;
        nv = nv_nxt;
    }
    unsafeAtomicAdd(agg + (size_t)cur * 128 + c, acc);
}

// ---------- K3: out = sigmoid(agg) * relu(beta) ----------
__global__ __launch_bounds__(256) void k_final(
    const float* __restrict__ agg, const float* __restrict__ beta,
    float4* __restrict__ out) {
    float rb = fmaxf(beta[0], 0.f);
    int i = blockIdx.x * 256 + threadIdx.x;
    int stride = gridDim.x * 256;
    const float4* a4 = (const float4*)agg;
    const int n4 = N_NODES * D_O / 4;
    for (; i < n4; i += stride) {
        float4 v = a4[i];
        float4 r;
        r.x = rb / (1.f + __expf(-v.x));
        r.y = rb / (1.f + __expf(-v.y));
        r.z = rb / (1.f + __expf(-v.z));
        r.w = rb / (1.f + __expf(-v.w));
        out[i] = r;
    }
}

// ---------- launch ----------
extern "C" void kernel_launch(void* const* d_in, const int* in_sizes, int n_in,
                              void* d_out, int out_size, void* d_ws, size_t ws_size,
                              hipStream_t stream) {
    const float* x    = (const float*)d_in[0];
    const float* ea   = (const float*)d_in[1];
    const float* Wx   = (const float*)d_in[2];
    const float* bx   = (const float*)d_in[3];
    const float* We   = (const float*)d_in[4];
    const float* be   = (const float*)d_in[5];
    const float* Wm   = (const float*)d_in[6];
    const float* bm   = (const float*)d_in[7];
    const float* beta = (const float*)d_in[8];
    const void*  ei   = d_in[9];

    // ws layout (byte offsets):
    //   A @0 (65536), B @65536 (16384), c @81920 (512), flag @82432 (64)
    //   srcA @131072, dstA @2691072, counts @5251072, cursor @5651072
    //   bsum @6051072, boff @6051584, offs @6052096
    //   perm @6452096, src_s @9012096, dst_s @11572096 (each 2,560,000)
    //   n2b @14132096 (25,600,000), agg @39732096 (51,200,000) -> 90,932,096
    if (ws_size < (size_t)90932096) return;

    char* ws = (char*)d_ws;
    float* A      = (float*)(ws);
    float* B      = (float*)(ws + 65536);
    float* c      = (float*)(ws + 81920);
    int*   flag   = (int*)(ws + 82432);
    int*   srcA   = (int*)(ws + 131072);
    int*   dstA   = (int*)(ws + 2691072);
    int*   counts = (int*)(ws + 5251072);
    int*   cursor = (int*)(ws + 5651072);
    int*   bsum   = (int*)(ws + 6051072);
    int*   boff   = (int*)(ws + 6051584);
    int*   offs   = (int*)(ws + 6052096);
    int*   perm   = (int*)(ws + 6452096);
    int*   src_s  = (int*)(ws + 9012096);
    int*   dst_s  = (int*)(ws + 11572096);
    u16*   n2b    = (u16*)(ws + 14132096);
    float* agg    = (float*)(ws + 39732096);

    k_fold<<<81, 256, 0, stream>>>(Wx, bx, We, be, Wm, bm, A, B, c);
    k_detect<<<1, 64, 0, stream>>>((const int*)ei, flag);
    k_zero<<<196, 256, 0, stream>>>((float4*)counts, 50000);      // counts+cursor
    k_zero<<<2048, 256, 0, stream>>>((float4*)agg, N_NODES * D_O / 4);
    k_extract_hist<<<2500, 256, 0, stream>>>(ei, flag, srcA, dstA, counts);
    k_scan_a<<<NB_SCAN, 256, 0, stream>>>(counts, bsum);
    k_scan_b<<<1, 64, 0, stream>>>(bsum, boff);
    k_scan_c<<<NB_SCAN, 256, 0, stream>>>(counts, boff, offs);
    k_scatter<<<2500, 256, 0, stream>>>(dstA, srcA, offs, cursor, perm, src_s, dst_s);
    k_node<<<N_NODES / 16, 256, 0, stream>>>(x, A, c, n2b);
    k_edge_mlp<<<NBLK_E, 256, 0, stream>>>(ea, perm, src_s, dst_s, B, n2b, agg);
    k_final<<<2048, 256, 0, stream>>>(agg, beta, (float4*)d_out);
}

// Round 7
// 422.991 us; speedup vs baseline: 3.3759x; 1.0300x over previous
//
#include <hip/hip_runtime.h>
#include <hip/hip_bf16.h>

#define N_NODES 100000
#define N_EDGES 640000
#define D_EE 32
#define D_O  128
#define SCAN_CHUNK 1024
#define NB_SCAN ((N_NODES + SCAN_CHUNK - 1) / SCAN_CHUNK)  // 98
#define EPB 256                       // edges per k_edge_mlp block
#define NBLK_E (N_EDGES / EPB)        // 2500
#define EAS 36                        // ea_s row stride in floats (144B, 16B-aligned)

typedef unsigned short u16;
typedef unsigned int u32;

// ---------- helpers ----------
__device__ __forceinline__ float4 fma4(float4 a, float s, float4 b) {
    a.x = fmaf(s, b.x, a.x);
    a.y = fmaf(s, b.y, a.y);
    a.z = fmaf(s, b.z, a.z);
    a.w = fmaf(s, b.w, a.w);
    return a;
}
__device__ __forceinline__ u16 f2bf(float f) {
    u32 b = __float_as_uint(f);
    return (u16)((b + 0x7FFFu + ((b >> 16) & 1u)) >> 16);  // RNE
}
__device__ __forceinline__ float bf2f(u16 u) {
    return __uint_as_float((u32)u << 16);
}

// ---------- K0: fold weights ----------
// A[i][j]=sum_k Wx[i][k]*Wm[k][j]; B[i][j]=sum_k We[i][k]*Wm[128+k][j]
// c[j]=bm[j]+sum_k bx[k]*Wm[k][j]+sum_k be[k]*Wm[128+k][j]
__global__ __launch_bounds__(256) void k_fold(
    const float* __restrict__ Wx, const float* __restrict__ bx,
    const float* __restrict__ We, const float* __restrict__ be,
    const float* __restrict__ Wm, const float* __restrict__ bm,
    float* __restrict__ A, float* __restrict__ B, float* __restrict__ c) {
    int idx = blockIdx.x * 256 + threadIdx.x;
    if (idx < 16384) {
        int i = idx >> 7, j = idx & 127;
        float s = 0.f;
        for (int k = 0; k < 128; ++k) s = fmaf(Wx[i * 128 + k], Wm[k * 128 + j], s);
        A[idx] = s;
    } else if (idx < 16384 + 4096) {
        int t = idx - 16384;
        int i = t >> 7, j = t & 127;
        float s = 0.f;
        for (int k = 0; k < 128; ++k) s = fmaf(We[i * 128 + k], Wm[(128 + k) * 128 + j], s);
        B[t] = s;
    } else if (idx < 16384 + 4096 + 128) {
        int j = idx - 20480;
        float s = bm[j];
        for (int k = 0; k < 128; ++k) s = fmaf(bx[k], Wm[k * 128 + j], s);
        for (int k = 0; k < 128; ++k) s = fmaf(be[k], Wm[(128 + k) * 128 + j], s);
        c[j] = s;
    }
}

// ---------- detect int32 vs int64 edge_index ----------
__global__ void k_detect(const int* __restrict__ ei, int* __restrict__ flag) {
    if (threadIdx.x == 0 && blockIdx.x == 0) {
        int o = 0;
        for (int i = 1; i < 64; i += 2) o |= ei[i];
        flag[0] = (o != 0) ? 1 : 0;  // 1 => int32, 0 => int64
    }
}

// ---------- zero (float4-wide) ----------
__global__ __launch_bounds__(256) void k_zero(float4* __restrict__ p, int n4) {
    int i = blockIdx.x * 256 + threadIdx.x;
    int stride = gridDim.x * 256;
    float4 z = make_float4(0.f, 0.f, 0.f, 0.f);
    for (; i < n4; i += stride) p[i] = z;
}

// ---------- extract indices + histogram of dst ----------
__global__ __launch_bounds__(256) void k_extract_hist(
    const void* __restrict__ ei_raw, const int* __restrict__ flag,
    int* __restrict__ srcA, int* __restrict__ dstA, int* __restrict__ counts) {
    int e = blockIdx.x * 256 + threadIdx.x;
    if (e >= N_EDGES) return;
    int src, dst;
    if (flag[0]) {
        const int* ei32 = (const int*)ei_raw;
        src = ei32[e];
        dst = ei32[N_EDGES + e];
    } else {
        const long long* ei64 = (const long long*)ei_raw;
        src = (int)ei64[e];
        dst = (int)ei64[N_EDGES + e];
    }
    srcA[e] = src;
    dstA[e] = dst;
    atomicAdd(&counts[dst], 1);
}

// ---------- scan A ----------
__global__ __launch_bounds__(256) void k_scan_a(
    const int* __restrict__ counts, int* __restrict__ bsum) {
    __shared__ int L[256];
    int b = blockIdx.x, t = threadIdx.x;
    int base = b * SCAN_CHUNK + t * 4;
    int s = 0;
#pragma unroll
    for (int r = 0; r < 4; ++r) {
        int i = base + r;
        if (i < N_NODES) s += counts[i];
    }
    L[t] = s;
    __syncthreads();
    for (int h = 128; h > 0; h >>= 1) {
        if (t < h) L[t] += L[t + h];
        __syncthreads();
    }
    if (t == 0) bsum[b] = L[0];
}

// ---------- scan B ----------
__global__ void k_scan_b(const int* __restrict__ bsum, int* __restrict__ boff) {
    if (threadIdx.x == 0 && blockIdx.x == 0) {
        int run = 0;
        for (int i = 0; i < NB_SCAN; ++i) { boff[i] = run; run += bsum[i]; }
    }
}

// ---------- scan C ----------
__global__ __launch_bounds__(256) void k_scan_c(
    const int* __restrict__ counts, const int* __restrict__ boff,
    int* __restrict__ offsets) {
    __shared__ int L[256];
    int b = blockIdx.x, t = threadIdx.x;
    int base = b * SCAN_CHUNK + t * 4;
    int c0 = 0, c1 = 0, c2 = 0, c3 = 0;
    if (base + 0 < N_NODES) c0 = counts[base + 0];
    if (base + 1 < N_NODES) c1 = counts[base + 1];
    if (base + 2 < N_NODES) c2 = counts[base + 2];
    if (base + 3 < N_NODES) c3 = counts[base + 3];
    L[t] = c0 + c1 + c2 + c3;
    __syncthreads();
    if (t == 0) {
        int run = 0;
        for (int i = 0; i < 256; ++i) { int tmp = L[i]; L[i] = run; run += tmp; }
    }
    __syncthreads();
    int o = boff[b] + L[t];
    if (base + 0 < N_NODES) offsets[base + 0] = o;
    if (base + 1 < N_NODES) offsets[base + 1] = o + c0;
    if (base + 2 < N_NODES) offsets[base + 2] = o + c0 + c1;
    if (base + 3 < N_NODES) offsets[base + 3] = o + c0 + c1 + c2;
}

// ---------- scatter: perm/src/dst in dst-sorted order ----------
__global__ __launch_bounds__(256) void k_scatter(
    const int* __restrict__ dstA, const int* __restrict__ srcA,
    const int* __restrict__ offsets, int* __restrict__ cursor,
    int* __restrict__ perm, int* __restrict__ src_s, int* __restrict__ dst_s) {
    int e = blockIdx.x * 256 + threadIdx.x;
    if (e >= N_EDGES) return;
    int d = dstA[e];
    int pos = offsets[d] + atomicAdd(&cursor[d], 1);
    perm[pos] = e;
    src_s[pos] = srcA[e];
    dst_s[pos] = d;
}

// ---------- K1: n2 = x @ A + c  -> bf16 [100000,128] ----------
__global__ __launch_bounds__(256) void k_node(
    const float* __restrict__ x, const float* __restrict__ A,
    const float* __restrict__ c, u16* __restrict__ n2b) {
    __shared__ float xs[16 * 128];
    int tid = threadIdx.x;
    int nb = blockIdx.x * 16;
    {
        const float4* xg = (const float4*)(x + (size_t)nb * 128);
        float4* xs4 = (float4*)xs;
        for (int i = tid; i < 512; i += 256) xs4[i] = xg[i];
    }
    __syncthreads();
    int tj = tid & 31, tn = tid >> 5;
    int j0 = tj * 4;
    float4 cc = *(const float4*)(c + j0);
    float4 acc0 = cc, acc1 = cc;
    const float* xr0 = xs + tn * 128;
    const float* xr1 = xs + (tn + 8) * 128;
    const float* Ap = A + j0;
#pragma unroll 4
    for (int k = 0; k < 128; k += 4) {
        float4 a0 = *(const float4*)(Ap + (size_t)(k + 0) * 128);
        float4 a1 = *(const float4*)(Ap + (size_t)(k + 1) * 128);
        float4 a2 = *(const float4*)(Ap + (size_t)(k + 2) * 128);
        float4 a3 = *(const float4*)(Ap + (size_t)(k + 3) * 128);
        float4 xa = *(const float4*)(xr0 + k);
        float4 xb = *(const float4*)(xr1 + k);
        acc0 = fma4(acc0, xa.x, a0); acc1 = fma4(acc1, xb.x, a0);
        acc0 = fma4(acc0, xa.y, a1); acc1 = fma4(acc1, xb.y, a1);
        acc0 = fma4(acc0, xa.z, a2); acc1 = fma4(acc1, xb.z, a2);
        acc0 = fma4(acc0, xa.w, a3); acc1 = fma4(acc1, xb.w, a3);
    }
    ushort4 o0 = make_ushort4(f2bf(acc0.x), f2bf(acc0.y), f2bf(acc0.z), f2bf(acc0.w));
    ushort4 o1 = make_ushort4(f2bf(acc1.x), f2bf(acc1.y), f2bf(acc1.z), f2bf(acc1.w));
    *(ushort4*)(n2b + (size_t)(nb + tn) * 128 + j0) = o0;
    *(ushort4*)(n2b + (size_t)(nb + tn + 8) * 128 + j0) = o1;
}

// ---------- K2: edge MLP, column-sweep over sorted edges ----------
// Block owns 256 sorted edges. Stage ea[256][32] in LDS (coalesced, once),
// row stride 36 floats (144B = 16B-aligned -> b128 reads; staging-write
// banks (4e+4q)%32 distinct per lane -> conflict-free).
// 256 threads = 128 cols x 2 halves; thread owns col c, B[:,c] in 32 VGPRs,
// sweeps 128 edges in dst-order via 8x ds_read_b128 + 32 FMA per edge,
// f32 run-accumulate in register; interior runs -> plain store,
// half-boundary runs -> atomic.
__global__ __launch_bounds__(256, 4) void k_edge_mlp(
    const float* __restrict__ ea, const int* __restrict__ perm,
    const int* __restrict__ src_s, const int* __restrict__ dst_s,
    const float* __restrict__ B, const u16* __restrict__ n2b,
    float* __restrict__ agg) {
    __shared__ float ea_s[EPB * EAS];
    __shared__ int src_l[EPB];
    __shared__ int dst_l[EPB];
    int tid = threadIdx.x;
    int base = blockIdx.x * EPB;
    src_l[tid] = src_s[base + tid];
    dst_l[tid] = dst_s[base + tid];
    {
        int q = tid & 7;               // float4 slot within 32-f row
        int e0 = tid >> 3;             // 0..31
#pragma unroll
        for (int ch = 0; ch < 8; ++ch) {
            int e = e0 + ch * 32;
            int p = perm[base + e];
            float4 v = *(const float4*)(ea + (size_t)p * 32 + q * 4);
            *(float4*)(&ea_s[e * EAS + q * 4]) = v;
        }
    }
    int c = tid & 127;
    int h = tid >> 7;
    float b[32];
#pragma unroll
    for (int k = 0; k < 32; ++k) b[k] = B[k * 128 + c];
    __syncthreads();

    int ebeg = h * 128, eend = ebeg + 128;
    float acc = 0.f;
    int cur = dst_l[ebeg];
    int nflush = 0;
    u16 nv = n2b[(size_t)src_l[ebeg] * 128 + c];
    for (int e = ebeg; e < eend; ++e) {
        u16 nv_nxt = 0;
        if (e + 1 < eend) nv_nxt = n2b[(size_t)src_l[e + 1] * 128 + c];
        int d = dst_l[e];
        if (d != cur) {
            float* ap = agg + (size_t)cur * 128 + c;
            if (nflush) *ap = acc;
            else unsafeAtomicAdd(ap, acc);
            ++nflush;
            acc = 0.f;
            cur = d;
        }
        const float4* er4 = (const float4*)(ea_s + e * EAS);
        float m0 = bf2f(nv), m1 = 0.f, m2 = 0.f, m3 = 0.f;
#pragma unroll
        for (int k4 = 0; k4 < 8; ++k4) {
            float4 v = er4[k4];
            m0 = fmaf(v.x, b[4 * k4 + 0], m0);
            m1 = fmaf(v.y, b[4 * k4 + 1], m1);
            m2 = fmaf(v.z, b[4 * k4 + 2], m2);
            m3 = fmaf(v.w, b[4 * k4 + 3], m3);
        }
        float m = (m0 + m1) + (m2 + m3);
        acc += (m > 0.f) ? m : 0.01f * m;
        nv = nv_nxt;
    }
    unsafeAtomicAdd(agg + (size_t)cur * 128 + c, acc);
}

// ---------- K3: out = sigmoid(agg) * relu(beta) ----------
__global__ __launch_bounds__(256) void k_final(
    const float* __restrict__ agg, const float* __restrict__ beta,
    float4* __restrict__ out) {
    float rb = fmaxf(beta[0], 0.f);
    int i = blockIdx.x * 256 + threadIdx.x;
    int stride = gridDim.x * 256;
    const float4* a4 = (const float4*)agg;
    const int n4 = N_NODES * D_O / 4;
    for (; i < n4; i += stride) {
        float4 v = a4[i];
        float4 r;
        r.x = rb / (1.f + __expf(-v.x));
        r.y = rb / (1.f + __expf(-v.y));
        r.z = rb / (1.f + __expf(-v.z));
        r.w = rb / (1.f + __expf(-v.w));
        out[i] = r;
    }
}

// ---------- launch ----------
extern "C" void kernel_launch(void* const* d_in, const int* in_sizes, int n_in,
                              void* d_out, int out_size, void* d_ws, size_t ws_size,
                              hipStream_t stream) {
    const float* x    = (const float*)d_in[0];
    const float* ea   = (const float*)d_in[1];
    const float* Wx   = (const float*)d_in[2];
    const float* bx   = (const float*)d_in[3];
    const float* We   = (const float*)d_in[4];
    const float* be   = (const float*)d_in[5];
    const float* Wm   = (const float*)d_in[6];
    const float* bm   = (const float*)d_in[7];
    const float* beta = (const float*)d_in[8];
    const void*  ei   = d_in[9];

    // ws layout (byte offsets):
    //   A @0 (65536), B @65536 (16384), c @81920 (512), flag @82432 (64)
    //   srcA @131072, dstA @2691072, counts @5251072, cursor @5651072
    //   bsum @6051072, boff @6051584, offs @6052096
    //   perm @6452096, src_s @9012096, dst_s @11572096 (each 2,560,000)
    //   n2b @14132096 (25,600,000), agg @39732096 (51,200,000) -> 90,932,096
    if (ws_size < (size_t)90932096) return;

    char* ws = (char*)d_ws;
    float* A      = (float*)(ws);
    float* B      = (float*)(ws + 65536);
    float* c      = (float*)(ws + 81920);
    int*   flag   = (int*)(ws + 82432);
    int*   srcA   = (int*)(ws + 131072);
    int*   dstA   = (int*)(ws + 2691072);
    int*   counts = (int*)(ws + 5251072);
    int*   cursor = (int*)(ws + 5651072);
    int*   bsum   = (int*)(ws + 6051072);
    int*   boff   = (int*)(ws + 6051584);
    int*   offs   = (int*)(ws + 6052096);
    int*   perm   = (int*)(ws + 6452096);
    int*   src_s  = (int*)(ws + 9012096);
    int*   dst_s  = (int*)(ws + 11572096);
    u16*   n2b    = (u16*)(ws + 14132096);
    float* agg    = (float*)(ws + 39732096);

    k_fold<<<81, 256, 0, stream>>>(Wx, bx, We, be, Wm, bm, A, B, c);
    k_detect<<<1, 64, 0, stream>>>((const int*)ei, flag);
    k_zero<<<196, 256, 0, stream>>>((float4*)counts, 50000);      // counts+cursor
    k_zero<<<2048, 256, 0, stream>>>((float4*)agg, N_NODES * D_O / 4);
    k_extract_hist<<<2500, 256, 0, stream>>>(ei, flag, srcA, dstA, counts);
    k_scan_a<<<NB_SCAN, 256, 0, stream>>>(counts, bsum);
    k_scan_b<<<1, 64, 0, stream>>>(bsum, boff);
    k_scan_c<<<NB_SCAN, 256, 0, stream>>>(counts, boff, offs);
    k_scatter<<<2500, 256, 0, stream>>>(dstA, srcA, offs, cursor, perm, src_s, dst_s);
    k_node<<<N_NODES / 16, 256, 0, stream>>>(x, A, c, n2b);
    k_edge_mlp<<<NBLK_E, 256, 0, stream>>>(ea, perm, src_s, dst_s, B, n2b, agg);
    k_final<<<2048, 256, 0, stream>>>(agg, beta, (float4*)d_out);
}

// Round 8
// 305.783 us; speedup vs baseline: 4.6699x; 1.3833x over previous
//
#include <hip/hip_runtime.h>
#include <hip/hip_bf16.h>

#define N_NODES 100000
#define N_EDGES 640000
#define D_EE 32
#define D_O  128
#define SCAN_CHUNK 1024
#define NB_SCAN ((N_NODES + SCAN_CHUNK - 1) / SCAN_CHUNK)  // 98
#define EPB 128                       // edges per k_edge_mlp block
#define NBLK_E (N_EDGES / EPB)        // 5000
#define EAS 40                        // ea_s row stride in bf16 (80B, 16B-aligned)
#define MSS 130                       // msg_s row stride in bf16

typedef unsigned short u16;
typedef unsigned int u32;
typedef short bf16x8 __attribute__((ext_vector_type(8)));
typedef float f32x4 __attribute__((ext_vector_type(4)));

// ---------- helpers ----------
__device__ __forceinline__ float4 fma4(float4 a, float s, float4 b) {
    a.x = fmaf(s, b.x, a.x);
    a.y = fmaf(s, b.y, a.y);
    a.z = fmaf(s, b.z, a.z);
    a.w = fmaf(s, b.w, a.w);
    return a;
}
__device__ __forceinline__ u16 f2bf(float f) {
    u32 b = __float_as_uint(f);
    return (u16)((b + 0x7FFFu + ((b >> 16) & 1u)) >> 16);  // RNE
}
__device__ __forceinline__ float bf2f(u16 u) {
    return __uint_as_float((u32)u << 16);
}

// ---------- K0: fold weights ----------
// A[i][j]=sum_k Wx[i][k]*Wm[k][j]; B[i][j]=sum_k We[i][k]*Wm[128+k][j]
// c[j]=bm[j]+sum_k bx[k]*Wm[k][j]+sum_k be[k]*Wm[128+k][j]
__global__ __launch_bounds__(256) void k_fold(
    const float* __restrict__ Wx, const float* __restrict__ bx,
    const float* __restrict__ We, const float* __restrict__ be,
    const float* __restrict__ Wm, const float* __restrict__ bm,
    float* __restrict__ A, float* __restrict__ B, float* __restrict__ c) {
    int idx = blockIdx.x * 256 + threadIdx.x;
    if (idx < 16384) {
        int i = idx >> 7, j = idx & 127;
        float s = 0.f;
        for (int k = 0; k < 128; ++k) s = fmaf(Wx[i * 128 + k], Wm[k * 128 + j], s);
        A[idx] = s;
    } else if (idx < 16384 + 4096) {
        int t = idx - 16384;
        int i = t >> 7, j = t & 127;
        float s = 0.f;
        for (int k = 0; k < 128; ++k) s = fmaf(We[i * 128 + k], Wm[(128 + k) * 128 + j], s);
        B[t] = s;
    } else if (idx < 16384 + 4096 + 128) {
        int j = idx - 20480;
        float s = bm[j];
        for (int k = 0; k < 128; ++k) s = fmaf(bx[k], Wm[k * 128 + j], s);
        for (int k = 0; k < 128; ++k) s = fmaf(be[k], Wm[(128 + k) * 128 + j], s);
        c[j] = s;
    }
}

// ---------- pack B into MFMA B-fragment order, bf16 ----------
// Bfrag[ct][lane][j] = bf16(B[(lane>>4)*8+j][ct*16+(lane&15)])
__global__ __launch_bounds__(256) void k_bfrag(
    const float* __restrict__ B, u16* __restrict__ Bfrag) {
    int idx = blockIdx.x * 256 + threadIdx.x;
    if (idx >= 4096) return;
    int ct = idx >> 9, l = (idx >> 3) & 63, j = idx & 7;
    int k = (l >> 4) * 8 + j, col = ct * 16 + (l & 15);
    Bfrag[ct * 512 + l * 8 + j] = f2bf(B[k * 128 + col]);
}

// ---------- detect int32 vs int64 edge_index ----------
__global__ void k_detect(const int* __restrict__ ei, int* __restrict__ flag) {
    if (threadIdx.x == 0 && blockIdx.x == 0) {
        int o = 0;
        for (int i = 1; i < 64; i += 2) o |= ei[i];
        flag[0] = (o != 0) ? 1 : 0;  // 1 => int32, 0 => int64
    }
}

// ---------- zero (float4-wide) ----------
__global__ __launch_bounds__(256) void k_zero(float4* __restrict__ p, int n4) {
    int i = blockIdx.x * 256 + threadIdx.x;
    int stride = gridDim.x * 256;
    float4 z = make_float4(0.f, 0.f, 0.f, 0.f);
    for (; i < n4; i += stride) p[i] = z;
}

// ---------- extract indices + histogram of dst ----------
__global__ __launch_bounds__(256) void k_extract_hist(
    const void* __restrict__ ei_raw, const int* __restrict__ flag,
    int* __restrict__ srcA, int* __restrict__ dstA, int* __restrict__ counts) {
    int e = blockIdx.x * 256 + threadIdx.x;
    if (e >= N_EDGES) return;
    int src, dst;
    if (flag[0]) {
        const int* ei32 = (const int*)ei_raw;
        src = ei32[e];
        dst = ei32[N_EDGES + e];
    } else {
        const long long* ei64 = (const long long*)ei_raw;
        src = (int)ei64[e];
        dst = (int)ei64[N_EDGES + e];
    }
    srcA[e] = src;
    dstA[e] = dst;
    atomicAdd(&counts[dst], 1);
}

// ---------- scan A ----------
__global__ __launch_bounds__(256) void k_scan_a(
    const int* __restrict__ counts, int* __restrict__ bsum) {
    __shared__ int L[256];
    int b = blockIdx.x, t = threadIdx.x;
    int base = b * SCAN_CHUNK + t * 4;
    int s = 0;
#pragma unroll
    for (int r = 0; r < 4; ++r) {
        int i = base + r;
        if (i < N_NODES) s += counts[i];
    }
    L[t] = s;
    __syncthreads();
    for (int h = 128; h > 0; h >>= 1) {
        if (t < h) L[t] += L[t + h];
        __syncthreads();
    }
    if (t == 0) bsum[b] = L[0];
}

// ---------- scan B ----------
__global__ void k_scan_b(const int* __restrict__ bsum, int* __restrict__ boff) {
    if (threadIdx.x == 0 && blockIdx.x == 0) {
        int run = 0;
        for (int i = 0; i < NB_SCAN; ++i) { boff[i] = run; run += bsum[i]; }
    }
}

// ---------- scan C ----------
__global__ __launch_bounds__(256) void k_scan_c(
    const int* __restrict__ counts, const int* __restrict__ boff,
    int* __restrict__ offsets) {
    __shared__ int L[256];
    int b = blockIdx.x, t = threadIdx.x;
    int base = b * SCAN_CHUNK + t * 4;
    int c0 = 0, c1 = 0, c2 = 0, c3 = 0;
    if (base + 0 < N_NODES) c0 = counts[base + 0];
    if (base + 1 < N_NODES) c1 = counts[base + 1];
    if (base + 2 < N_NODES) c2 = counts[base + 2];
    if (base + 3 < N_NODES) c3 = counts[base + 3];
    L[t] = c0 + c1 + c2 + c3;
    __syncthreads();
    if (t == 0) {
        int run = 0;
        for (int i = 0; i < 256; ++i) { int tmp = L[i]; L[i] = run; run += tmp; }
    }
    __syncthreads();
    int o = boff[b] + L[t];
    if (base + 0 < N_NODES) offsets[base + 0] = o;
    if (base + 1 < N_NODES) offsets[base + 1] = o + c0;
    if (base + 2 < N_NODES) offsets[base + 2] = o + c0 + c1;
    if (base + 3 < N_NODES) offsets[base + 3] = o + c0 + c1 + c2;
}

// ---------- scatter: perm/src/dst in dst-sorted order ----------
__global__ __launch_bounds__(256) void k_scatter(
    const int* __restrict__ dstA, const int* __restrict__ srcA,
    const int* __restrict__ offsets, int* __restrict__ cursor,
    int* __restrict__ perm, int* __restrict__ src_s, int* __restrict__ dst_s) {
    int e = blockIdx.x * 256 + threadIdx.x;
    if (e >= N_EDGES) return;
    int d = dstA[e];
    int pos = offsets[d] + atomicAdd(&cursor[d], 1);
    perm[pos] = e;
    src_s[pos] = srcA[e];
    dst_s[pos] = d;
}

// ---------- K1: n2 = x @ A + c  -> bf16 [100000,128] ----------
__global__ __launch_bounds__(256) void k_node(
    const float* __restrict__ x, const float* __restrict__ A,
    const float* __restrict__ c, u16* __restrict__ n2b) {
    __shared__ float xs[16 * 128];
    int tid = threadIdx.x;
    int nb = blockIdx.x * 16;
    {
        const float4* xg = (const float4*)(x + (size_t)nb * 128);
        float4* xs4 = (float4*)xs;
        for (int i = tid; i < 512; i += 256) xs4[i] = xg[i];
    }
    __syncthreads();
    int tj = tid & 31, tn = tid >> 5;
    int j0 = tj * 4;
    float4 cc = *(const float4*)(c + j0);
    float4 acc0 = cc, acc1 = cc;
    const float* xr0 = xs + tn * 128;
    const float* xr1 = xs + (tn + 8) * 128;
    const float* Ap = A + j0;
#pragma unroll 4
    for (int k = 0; k < 128; k += 4) {
        float4 a0 = *(const float4*)(Ap + (size_t)(k + 0) * 128);
        float4 a1 = *(const float4*)(Ap + (size_t)(k + 1) * 128);
        float4 a2 = *(const float4*)(Ap + (size_t)(k + 2) * 128);
        float4 a3 = *(const float4*)(Ap + (size_t)(k + 3) * 128);
        float4 xa = *(const float4*)(xr0 + k);
        float4 xb = *(const float4*)(xr1 + k);
        acc0 = fma4(acc0, xa.x, a0); acc1 = fma4(acc1, xb.x, a0);
        acc0 = fma4(acc0, xa.y, a1); acc1 = fma4(acc1, xb.y, a1);
        acc0 = fma4(acc0, xa.z, a2); acc1 = fma4(acc1, xb.z, a2);
        acc0 = fma4(acc0, xa.w, a3); acc1 = fma4(acc1, xb.w, a3);
    }
    ushort4 o0 = make_ushort4(f2bf(acc0.x), f2bf(acc0.y), f2bf(acc0.z), f2bf(acc0.w));
    ushort4 o1 = make_ushort4(f2bf(acc1.x), f2bf(acc1.y), f2bf(acc1.z), f2bf(acc1.w));
    *(ushort4*)(n2b + (size_t)(nb + tn) * 128 + j0) = o0;
    *(ushort4*)(n2b + (size_t)(nb + tn + 8) * 128 + j0) = o1;
}

// ---------- K2: edge MLP via MFMA + LDS msg + column sweep ----------
// Block owns 128 sorted edges. Stage ea rows -> LDS bf16 (stride 40).
// 4 waves x {2 edge-tiles x 8 col-tiles} mfma_f32_16x16x32_bf16:
// A-frag: lane reads ea_s[(etb+(l&15))*40 + (l>>4)*8 ..+8] (one b128).
// B-frag: fragment-ordered Bfrag global, one dwordx4/lane/ct (L2-hot).
// C layout (m89): col=lane&15 (+16*ct), row=(lane>>4)*4+r (+16*et+32*w).
// Epilogue: + n2b[src] gather, leaky, msg -> LDS bf16 (stride 130).
// Sweep: thread owns col, 64 edges/half; run-accumulate; interior run ->
// plain store, boundary -> atomic (proven r6/r7 logic).
__global__ __launch_bounds__(256, 3) void k_edge_mlp(
    const float* __restrict__ ea, const int* __restrict__ perm,
    const int* __restrict__ src_s, const int* __restrict__ dst_s,
    const u16* __restrict__ Bfrag, const u16* __restrict__ n2b,
    float* __restrict__ agg) {
    __shared__ u16 ea_s[EPB * EAS];     // 10240 B
    __shared__ u16 msg_s[EPB * MSS];    // 33280 B
    __shared__ int src_l[EPB];
    __shared__ int dst_l[EPB];
    int tid = threadIdx.x;
    int base = blockIdx.x * EPB;
    if (tid < EPB) {
        src_l[tid] = src_s[base + tid];
        dst_l[tid] = dst_s[base + tid];
    }
    {   // stage ea rows f32 -> bf16: thread t does row t>>1, half t&1
        int row = tid >> 1, q = tid & 1;
        int p = perm[base + row];
        const float4* s4 = (const float4*)(ea + (size_t)p * 32 + q * 16);
        float4 v0 = s4[0], v1 = s4[1], v2 = s4[2], v3 = s4[3];
        u16* wp = &ea_s[row * EAS + q * 16];
        *(ushort4*)(wp + 0)  = make_ushort4(f2bf(v0.x), f2bf(v0.y), f2bf(v0.z), f2bf(v0.w));
        *(ushort4*)(wp + 4)  = make_ushort4(f2bf(v1.x), f2bf(v1.y), f2bf(v1.z), f2bf(v1.w));
        *(ushort4*)(wp + 8)  = make_ushort4(f2bf(v2.x), f2bf(v2.y), f2bf(v2.z), f2bf(v2.w));
        *(ushort4*)(wp + 12) = make_ushort4(f2bf(v3.x), f2bf(v3.y), f2bf(v3.z), f2bf(v3.w));
    }
    int lane = tid & 63, wv = tid >> 6;
    int l15 = lane & 15, l4 = lane >> 4;
    bf16x8 bfr[8];
#pragma unroll
    for (int ct = 0; ct < 8; ++ct)
        bfr[ct] = *(const bf16x8*)(Bfrag + ct * 512 + lane * 8);
    __syncthreads();

#pragma unroll
    for (int et = 0; et < 2; ++et) {
        int etb = wv * 32 + et * 16;
        bf16x8 af = *(const bf16x8*)(&ea_s[(etb + l15) * EAS + l4 * 8]);
        int e0 = etb + l4 * 4;
        const u16* nr0 = n2b + (size_t)src_l[e0 + 0] * 128;
        const u16* nr1 = n2b + (size_t)src_l[e0 + 1] * 128;
        const u16* nr2 = n2b + (size_t)src_l[e0 + 2] * 128;
        const u16* nr3 = n2b + (size_t)src_l[e0 + 3] * 128;
#pragma unroll
        for (int ct = 0; ct < 8; ++ct) {
            f32x4 acc = {0.f, 0.f, 0.f, 0.f};
            acc = __builtin_amdgcn_mfma_f32_16x16x32_bf16(af, bfr[ct], acc, 0, 0, 0);
            int col = ct * 16 + l15;
            float m0 = acc[0] + bf2f(nr0[col]);
            float m1 = acc[1] + bf2f(nr1[col]);
            float m2 = acc[2] + bf2f(nr2[col]);
            float m3 = acc[3] + bf2f(nr3[col]);
            m0 = m0 > 0.f ? m0 : 0.01f * m0;
            m1 = m1 > 0.f ? m1 : 0.01f * m1;
            m2 = m2 > 0.f ? m2 : 0.01f * m2;
            m3 = m3 > 0.f ? m3 : 0.01f * m3;
            msg_s[(e0 + 0) * MSS + col] = f2bf(m0);
            msg_s[(e0 + 1) * MSS + col] = f2bf(m1);
            msg_s[(e0 + 2) * MSS + col] = f2bf(m2);
            msg_s[(e0 + 3) * MSS + col] = f2bf(m3);
        }
    }
    __syncthreads();

    int c = tid & 127, h = tid >> 7;
    int ebeg = h * 64, eend = ebeg + 64;
    float acc = 0.f;
    int cur = dst_l[ebeg];
    int nflush = 0;
    for (int e = ebeg; e < eend; ++e) {
        int d = dst_l[e];
        if (d != cur) {
            float* ap = agg + (size_t)cur * 128 + c;
            if (nflush) *ap = acc;
            else unsafeAtomicAdd(ap, acc);
            ++nflush;
            acc = 0.f;
            cur = d;
        }
        acc += bf2f(msg_s[e * MSS + c]);
    }
    unsafeAtomicAdd(agg + (size_t)cur * 128 + c, acc);
}

// ---------- K3: out = sigmoid(agg) * relu(beta) ----------
__global__ __launch_bounds__(256) void k_final(
    const float* __restrict__ agg, const float* __restrict__ beta,
    float4* __restrict__ out) {
    float rb = fmaxf(beta[0], 0.f);
    int i = blockIdx.x * 256 + threadIdx.x;
    int stride = gridDim.x * 256;
    const float4* a4 = (const float4*)agg;
    const int n4 = N_NODES * D_O / 4;
    for (; i < n4; i += stride) {
        float4 v = a4[i];
        float4 r;
        r.x = rb / (1.f + __expf(-v.x));
        r.y = rb / (1.f + __expf(-v.y));
        r.z = rb / (1.f + __expf(-v.z));
        r.w = rb / (1.f + __expf(-v.w));
        out[i] = r;
    }
}

// ---------- launch ----------
extern "C" void kernel_launch(void* const* d_in, const int* in_sizes, int n_in,
                              void* d_out, int out_size, void* d_ws, size_t ws_size,
                              hipStream_t stream) {
    const float* x    = (const float*)d_in[0];
    const float* ea   = (const float*)d_in[1];
    const float* Wx   = (const float*)d_in[2];
    const float* bx   = (const float*)d_in[3];
    const float* We   = (const float*)d_in[4];
    const float* be   = (const float*)d_in[5];
    const float* Wm   = (const float*)d_in[6];
    const float* bm   = (const float*)d_in[7];
    const float* beta = (const float*)d_in[8];
    const void*  ei   = d_in[9];

    // ws layout (byte offsets):
    //   A @0 (65536), B @65536 (16384), c @81920 (512), flag @82432 (64)
    //   Bfrag @82496 (8192) -> 90688
    //   srcA @131072, dstA @2691072, counts @5251072, cursor @5651072
    //   bsum @6051072, boff @6051584, offs @6052096
    //   perm @6452096, src_s @9012096, dst_s @11572096 (each 2,560,000)
    //   n2b @14132096 (25,600,000), agg @39732096 (51,200,000) -> 90,932,096
    if (ws_size < (size_t)90932096) return;

    char* ws = (char*)d_ws;
    float* A      = (float*)(ws);
    float* B      = (float*)(ws + 65536);
    float* c      = (float*)(ws + 81920);
    int*   flag   = (int*)(ws + 82432);
    u16*   Bfrag  = (u16*)(ws + 82496);
    int*   srcA   = (int*)(ws + 131072);
    int*   dstA   = (int*)(ws + 2691072);
    int*   counts = (int*)(ws + 5251072);
    int*   cursor = (int*)(ws + 5651072);
    int*   bsum   = (int*)(ws + 6051072);
    int*   boff   = (int*)(ws + 6051584);
    int*   offs   = (int*)(ws + 6052096);
    int*   perm   = (int*)(ws + 6452096);
    int*   src_s  = (int*)(ws + 9012096);
    int*   dst_s  = (int*)(ws + 11572096);
    u16*   n2b    = (u16*)(ws + 14132096);
    float* agg    = (float*)(ws + 39732096);

    k_fold<<<81, 256, 0, stream>>>(Wx, bx, We, be, Wm, bm, A, B, c);
    k_bfrag<<<16, 256, 0, stream>>>(B, Bfrag);
    k_detect<<<1, 64, 0, stream>>>((const int*)ei, flag);
    k_zero<<<196, 256, 0, stream>>>((float4*)counts, 50000);      // counts+cursor
    k_zero<<<2048, 256, 0, stream>>>((float4*)agg, N_NODES * D_O / 4);
    k_extract_hist<<<2500, 256, 0, stream>>>(ei, flag, srcA, dstA, counts);
    k_scan_a<<<NB_SCAN, 256, 0, stream>>>(counts, bsum);
    k_scan_b<<<1, 64, 0, stream>>>(bsum, boff);
    k_scan_c<<<NB_SCAN, 256, 0, stream>>>(counts, boff, offs);
    k_scatter<<<2500, 256, 0, stream>>>(dstA, srcA, offs, cursor, perm, src_s, dst_s);
    k_node<<<N_NODES / 16, 256, 0, stream>>>(x, A, c, n2b);
    k_edge_mlp<<<NBLK_E, 256, 0, stream>>>(ea, perm, src_s, dst_s, Bfrag, n2b, agg);
    k_final<<<2048, 256, 0, stream>>>(agg, beta, (float4*)d_out);
}

// Round 9
// 229.931 us; speedup vs baseline: 6.2104x; 1.3299x over previous
//
#include <hip/hip_runtime.h>
#include <hip/hip_bf16.h>

#define N_NODES 100000
#define N_EDGES 640000
#define D_EE 32
#define D_O  128
#define SCAN_CHUNK 1024
#define NB_SCAN ((N_NODES + SCAN_CHUNK - 1) / SCAN_CHUNK)  // 98
#define EPB 128                       // edges per k_edge_mlp block
#define NBLK_E (N_EDGES / EPB)        // 5000
#define EAS 40                        // ea_s row stride in bf16 (80B, 16B-aligned)
#define MSS 130                       // msg_s row stride in bf16
#define XNS 64                        // nodes per k_node block
#define XRS 136                       // x_s row stride in bf16 (272B, 16B-aligned)

typedef unsigned short u16;
typedef unsigned int u32;
typedef short bf16x8 __attribute__((ext_vector_type(8)));
typedef float f32x4 __attribute__((ext_vector_type(4)));

// ---------- helpers ----------
__device__ __forceinline__ u16 f2bf(float f) {
    u32 b = __float_as_uint(f);
    return (u16)((b + 0x7FFFu + ((b >> 16) & 1u)) >> 16);  // RNE
}
__device__ __forceinline__ float bf2f(u16 u) {
    return __uint_as_float((u32)u << 16);
}

// ---------- K0: fold weights ----------
// A[i][j]=sum_k Wx[i][k]*Wm[k][j]; B[i][j]=sum_k We[i][k]*Wm[128+k][j]
// c[j]=bm[j]+sum_k bx[k]*Wm[k][j]+sum_k be[k]*Wm[128+k][j]
__global__ __launch_bounds__(256) void k_fold(
    const float* __restrict__ Wx, const float* __restrict__ bx,
    const float* __restrict__ We, const float* __restrict__ be,
    const float* __restrict__ Wm, const float* __restrict__ bm,
    float* __restrict__ A, float* __restrict__ B, float* __restrict__ c) {
    int idx = blockIdx.x * 256 + threadIdx.x;
    if (idx < 16384) {
        int i = idx >> 7, j = idx & 127;
        float s = 0.f;
        for (int k = 0; k < 128; ++k) s = fmaf(Wx[i * 128 + k], Wm[k * 128 + j], s);
        A[idx] = s;
    } else if (idx < 16384 + 4096) {
        int t = idx - 16384;
        int i = t >> 7, j = t & 127;
        float s = 0.f;
        for (int k = 0; k < 128; ++k) s = fmaf(We[i * 128 + k], Wm[(128 + k) * 128 + j], s);
        B[t] = s;
    } else if (idx < 16384 + 4096 + 128) {
        int j = idx - 20480;
        float s = bm[j];
        for (int k = 0; k < 128; ++k) s = fmaf(bx[k], Wm[k * 128 + j], s);
        for (int k = 0; k < 128; ++k) s = fmaf(be[k], Wm[(128 + k) * 128 + j], s);
        c[j] = s;
    }
}

// ---------- pack B into MFMA B-fragment order, bf16 ----------
// Bfrag[ct][lane][j] = bf16(B[(lane>>4)*8+j][ct*16+(lane&15)])
__global__ __launch_bounds__(256) void k_bfrag(
    const float* __restrict__ B, u16* __restrict__ Bfrag) {
    int idx = blockIdx.x * 256 + threadIdx.x;
    if (idx >= 4096) return;
    int ct = idx >> 9, l = (idx >> 3) & 63, j = idx & 7;
    int k = (l >> 4) * 8 + j, col = ct * 16 + (l & 15);
    Bfrag[ct * 512 + l * 8 + j] = f2bf(B[k * 128 + col]);
}

// ---------- pack folded A into MFMA B-fragment order, bf16 ----------
// Afrag[ks][ct][lane][j] = bf16(A[ks*32+(lane>>4)*8+j][ct*16+(lane&15)])
__global__ __launch_bounds__(256) void k_afrag(
    const float* __restrict__ A, u16* __restrict__ Afrag) {
    int idx = blockIdx.x * 256 + threadIdx.x;
    if (idx >= 16384) return;
    int ks = idx >> 12, ct = (idx >> 9) & 7, l = (idx >> 3) & 63, j = idx & 7;
    int k = ks * 32 + (l >> 4) * 8 + j, col = ct * 16 + (l & 15);
    Afrag[idx] = f2bf(A[k * 128 + col]);
}

// ---------- detect int32 vs int64 edge_index ----------
__global__ void k_detect(const int* __restrict__ ei, int* __restrict__ flag) {
    if (threadIdx.x == 0 && blockIdx.x == 0) {
        int o = 0;
        for (int i = 1; i < 64; i += 2) o |= ei[i];
        flag[0] = (o != 0) ? 1 : 0;  // 1 => int32, 0 => int64
    }
}

// ---------- zero (float4-wide) ----------
__global__ __launch_bounds__(256) void k_zero(float4* __restrict__ p, int n4) {
    int i = blockIdx.x * 256 + threadIdx.x;
    int stride = gridDim.x * 256;
    float4 z = make_float4(0.f, 0.f, 0.f, 0.f);
    for (; i < n4; i += stride) p[i] = z;
}

// ---------- extract indices + histogram of dst ----------
__global__ __launch_bounds__(256) void k_extract_hist(
    const void* __restrict__ ei_raw, const int* __restrict__ flag,
    int* __restrict__ srcA, int* __restrict__ dstA, int* __restrict__ counts) {
    int e = blockIdx.x * 256 + threadIdx.x;
    if (e >= N_EDGES) return;
    int src, dst;
    if (flag[0]) {
        const int* ei32 = (const int*)ei_raw;
        src = ei32[e];
        dst = ei32[N_EDGES + e];
    } else {
        const long long* ei64 = (const long long*)ei_raw;
        src = (int)ei64[e];
        dst = (int)ei64[N_EDGES + e];
    }
    srcA[e] = src;
    dstA[e] = dst;
    atomicAdd(&counts[dst], 1);
}

// ---------- scan A ----------
__global__ __launch_bounds__(256) void k_scan_a(
    const int* __restrict__ counts, int* __restrict__ bsum) {
    __shared__ int L[256];
    int b = blockIdx.x, t = threadIdx.x;
    int base = b * SCAN_CHUNK + t * 4;
    int s = 0;
#pragma unroll
    for (int r = 0; r < 4; ++r) {
        int i = base + r;
        if (i < N_NODES) s += counts[i];
    }
    L[t] = s;
    __syncthreads();
    for (int h = 128; h > 0; h >>= 1) {
        if (t < h) L[t] += L[t + h];
        __syncthreads();
    }
    if (t == 0) bsum[b] = L[0];
}

// ---------- scan B ----------
__global__ void k_scan_b(const int* __restrict__ bsum, int* __restrict__ boff) {
    if (threadIdx.x == 0 && blockIdx.x == 0) {
        int run = 0;
        for (int i = 0; i < NB_SCAN; ++i) { boff[i] = run; run += bsum[i]; }
    }
}

// ---------- scan C ----------
__global__ __launch_bounds__(256) void k_scan_c(
    const int* __restrict__ counts, const int* __restrict__ boff,
    int* __restrict__ offsets) {
    __shared__ int L[256];
    int b = blockIdx.x, t = threadIdx.x;
    int base = b * SCAN_CHUNK + t * 4;
    int c0 = 0, c1 = 0, c2 = 0, c3 = 0;
    if (base + 0 < N_NODES) c0 = counts[base + 0];
    if (base + 1 < N_NODES) c1 = counts[base + 1];
    if (base + 2 < N_NODES) c2 = counts[base + 2];
    if (base + 3 < N_NODES) c3 = counts[base + 3];
    L[t] = c0 + c1 + c2 + c3;
    __syncthreads();
    if (t == 0) {
        int run = 0;
        for (int i = 0; i < 256; ++i) { int tmp = L[i]; L[i] = run; run += tmp; }
    }
    __syncthreads();
    int o = boff[b] + L[t];
    if (base + 0 < N_NODES) offsets[base + 0] = o;
    if (base + 1 < N_NODES) offsets[base + 1] = o + c0;
    if (base + 2 < N_NODES) offsets[base + 2] = o + c0 + c1;
    if (base + 3 < N_NODES) offsets[base + 3] = o + c0 + c1 + c2;
}

// ---------- scatter: perm/src/dst in dst-sorted order ----------
__global__ __launch_bounds__(256) void k_scatter(
    const int* __restrict__ dstA, const int* __restrict__ srcA,
    const int* __restrict__ offsets, int* __restrict__ cursor,
    int* __restrict__ perm, int* __restrict__ src_s, int* __restrict__ dst_s) {
    int e = blockIdx.x * 256 + threadIdx.x;
    if (e >= N_EDGES) return;
    int d = dstA[e];
    int pos = offsets[d] + atomicAdd(&cursor[d], 1);
    perm[pos] = e;
    src_s[pos] = srcA[e];
    dst_s[pos] = d;
}

// ---------- K1: n2 = x @ A + c  via MFMA -> bf16 [100000,128] ----------
// Block = 64 nodes. Stage x -> LDS bf16 (stride 136: fragment reads 2-way
// free). Wave wv computes nodes [wv*16, wv*16+16): 4 k-steps x 8 col-tiles
// mfma_f32_16x16x32_bf16, acc init = c[col] (bias via C operand).
// A-frag: lane reads x_s[(w16+l15)*136 + ks*32 + l4*8 ..+8] (one b128).
// B-frag: Afrag global, dwordx4/lane, L1-hot (32KB shared by all blocks).
// C layout (verified r8): col = ct*16+l15, row = w16 + l4*4 + r.
__global__ __launch_bounds__(256, 4) void k_node(
    const float* __restrict__ x, const u16* __restrict__ Afrag,
    const float* __restrict__ c, u16* __restrict__ n2b) {
    __shared__ u16 x_s[XNS * XRS];
    int tid = threadIdx.x;
    int nb = blockIdx.x * XNS;
    {
        int row = tid >> 2, q = tid & 3;
        int node = nb + row;
        u16* wp = &x_s[row * XRS + q * 32];
        if (node < N_NODES) {
            const float4* src = (const float4*)(x + (size_t)node * 128 + q * 32);
#pragma unroll
            for (int i = 0; i < 8; ++i) {
                float4 v = src[i];
                *(ushort4*)(wp + i * 4) =
                    make_ushort4(f2bf(v.x), f2bf(v.y), f2bf(v.z), f2bf(v.w));
            }
        } else {
#pragma unroll
            for (int i = 0; i < 8; ++i)
                *(ushort4*)(wp + i * 4) = make_ushort4(0, 0, 0, 0);
        }
    }
    int lane = tid & 63, wv = tid >> 6;
    int l15 = lane & 15, l4 = lane >> 4;
    f32x4 acc[8];
#pragma unroll
    for (int ct = 0; ct < 8; ++ct) {
        float cv = c[ct * 16 + l15];
        acc[ct] = (f32x4){cv, cv, cv, cv};
    }
    __syncthreads();
    int w16 = wv * 16;
#pragma unroll
    for (int ks = 0; ks < 4; ++ks) {
        bf16x8 af = *(const bf16x8*)(&x_s[(w16 + l15) * XRS + ks * 32 + l4 * 8]);
#pragma unroll
        for (int ct = 0; ct < 8; ++ct) {
            bf16x8 bf = *(const bf16x8*)(Afrag + (size_t)(ks * 8 + ct) * 512 + lane * 8);
            acc[ct] = __builtin_amdgcn_mfma_f32_16x16x32_bf16(af, bf, acc[ct], 0, 0, 0);
        }
    }
    int node0 = nb + w16 + l4 * 4;
#pragma unroll
    for (int ct = 0; ct < 8; ++ct) {
        int col = ct * 16 + l15;
#pragma unroll
        for (int r = 0; r < 4; ++r) {
            int node = node0 + r;
            if (node < N_NODES) n2b[(size_t)node * 128 + col] = f2bf(acc[ct][r]);
        }
    }
}

// ---------- K2: edge MLP via MFMA + LDS msg + column sweep ----------
// (verified r8) Block owns 128 sorted edges; ea -> LDS bf16; 4 waves x
// {2 edge-tiles x 8 col-tiles} MFMA; epilogue + n2b[src], leaky, msg->LDS;
// column sweep with run-accumulate, boundary atomics.
__global__ __launch_bounds__(256, 3) void k_edge_mlp(
    const float* __restrict__ ea, const int* __restrict__ perm,
    const int* __restrict__ src_s, const int* __restrict__ dst_s,
    const u16* __restrict__ Bfrag, const u16* __restrict__ n2b,
    float* __restrict__ agg) {
    __shared__ u16 ea_s[EPB * EAS];     // 10240 B
    __shared__ u16 msg_s[EPB * MSS];    // 33280 B
    __shared__ int src_l[EPB];
    __shared__ int dst_l[EPB];
    int tid = threadIdx.x;
    int base = blockIdx.x * EPB;
    if (tid < EPB) {
        src_l[tid] = src_s[base + tid];
        dst_l[tid] = dst_s[base + tid];
    }
    {   // stage ea rows f32 -> bf16: thread t does row t>>1, half t&1
        int row = tid >> 1, q = tid & 1;
        int p = perm[base + row];
        const float4* s4 = (const float4*)(ea + (size_t)p * 32 + q * 16);
        float4 v0 = s4[0], v1 = s4[1], v2 = s4[2], v3 = s4[3];
        u16* wp = &ea_s[row * EAS + q * 16];
        *(ushort4*)(wp + 0)  = make_ushort4(f2bf(v0.x), f2bf(v0.y), f2bf(v0.z), f2bf(v0.w));
        *(ushort4*)(wp + 4)  = make_ushort4(f2bf(v1.x), f2bf(v1.y), f2bf(v1.z), f2bf(v1.w));
        *(ushort4*)(wp + 8)  = make_ushort4(f2bf(v2.x), f2bf(v2.y), f2bf(v2.z), f2bf(v2.w));
        *(ushort4*)(wp + 12) = make_ushort4(f2bf(v3.x), f2bf(v3.y), f2bf(v3.z), f2bf(v3.w));
    }
    int lane = tid & 63, wv = tid >> 6;
    int l15 = lane & 15, l4 = lane >> 4;
    bf16x8 bfr[8];
#pragma unroll
    for (int ct = 0; ct < 8; ++ct)
        bfr[ct] = *(const bf16x8*)(Bfrag + ct * 512 + lane * 8);
    __syncthreads();

#pragma unroll
    for (int et = 0; et < 2; ++et) {
        int etb = wv * 32 + et * 16;
        bf16x8 af = *(const bf16x8*)(&ea_s[(etb + l15) * EAS + l4 * 8]);
        int e0 = etb + l4 * 4;
        const u16* nr0 = n2b + (size_t)src_l[e0 + 0] * 128;
        const u16* nr1 = n2b + (size_t)src_l[e0 + 1] * 128;
        const u16* nr2 = n2b + (size_t)src_l[e0 + 2] * 128;
        const u16* nr3 = n2b + (size_t)src_l[e0 + 3] * 128;
#pragma unroll
        for (int ct = 0; ct < 8; ++ct) {
            f32x4 acc = {0.f, 0.f, 0.f, 0.f};
            acc = __builtin_amdgcn_mfma_f32_16x16x32_bf16(af, bfr[ct], acc, 0, 0, 0);
            int col = ct * 16 + l15;
            float m0 = acc[0] + bf2f(nr0[col]);
            float m1 = acc[1] + bf2f(nr1[col]);
            float m2 = acc[2] + bf2f(nr2[col]);
            float m3 = acc[3] + bf2f(nr3[col]);
            m0 = m0 > 0.f ? m0 : 0.01f * m0;
            m1 = m1 > 0.f ? m1 : 0.01f * m1;
            m2 = m2 > 0.f ? m2 : 0.01f * m2;
            m3 = m3 > 0.f ? m3 : 0.01f * m3;
            msg_s[(e0 + 0) * MSS + col] = f2bf(m0);
            msg_s[(e0 + 1) * MSS + col] = f2bf(m1);
            msg_s[(e0 + 2) * MSS + col] = f2bf(m2);
            msg_s[(e0 + 3) * MSS + col] = f2bf(m3);
        }
    }
    __syncthreads();

    int c = tid & 127, h = tid >> 7;
    int ebeg = h * 64, eend = ebeg + 64;
    float acc = 0.f;
    int cur = dst_l[ebeg];
    int nflush = 0;
    for (int e = ebeg; e < eend; ++e) {
        int d = dst_l[e];
        if (d != cur) {
            float* ap = agg + (size_t)cur * 128 + c;
            if (nflush) *ap = acc;
            else unsafeAtomicAdd(ap, acc);
            ++nflush;
            acc = 0.f;
            cur = d;
        }
        acc += bf2f(msg_s[e * MSS + c]);
    }
    unsafeAtomicAdd(agg + (size_t)cur * 128 + c, acc);
}

// ---------- K3: out = sigmoid(agg) * relu(beta) ----------
__global__ __launch_bounds__(256) void k_final(
    const float* __restrict__ agg, const float* __restrict__ beta,
    float4* __restrict__ out) {
    float rb = fmaxf(beta[0], 0.f);
    int i = blockIdx.x * 256 + threadIdx.x;
    int stride = gridDim.x * 256;
    const float4* a4 = (const float4*)agg;
    const int n4 = N_NODES * D_O / 4;
    for (; i < n4; i += stride) {
        float4 v = a4[i];
        float4 r;
        r.x = rb / (1.f + __expf(-v.x));
        r.y = rb / (1.f + __expf(-v.y));
        r.z = rb / (1.f + __expf(-v.z));
        r.w = rb / (1.f + __expf(-v.w));
        out[i] = r;
    }
}

// ---------- launch ----------
extern "C" void kernel_launch(void* const* d_in, const int* in_sizes, int n_in,
                              void* d_out, int out_size, void* d_ws, size_t ws_size,
                              hipStream_t stream) {
    const float* x    = (const float*)d_in[0];
    const float* ea   = (const float*)d_in[1];
    const float* Wx   = (const float*)d_in[2];
    const float* bx   = (const float*)d_in[3];
    const float* We   = (const float*)d_in[4];
    const float* be   = (const float*)d_in[5];
    const float* Wm   = (const float*)d_in[6];
    const float* bm   = (const float*)d_in[7];
    const float* beta = (const float*)d_in[8];
    const void*  ei   = d_in[9];

    // ws layout (byte offsets):
    //   A @0 (65536), B @65536 (16384), c @81920 (512), flag @82432 (64)
    //   Bfrag @82496 (8192), Afrag @90688 (32768) -> 123456
    //   srcA @131072, dstA @2691072, counts @5251072, cursor @5651072
    //   bsum @6051072, boff @6051584, offs @6052096
    //   perm @6452096, src_s @9012096, dst_s @11572096 (each 2,560,000)
    //   n2b @14132096 (25,600,000), agg @39732096 (51,200,000) -> 90,932,096
    if (ws_size < (size_t)90932096) return;

    char* ws = (char*)d_ws;
    float* A      = (float*)(ws);
    float* B      = (float*)(ws + 65536);
    float* c      = (float*)(ws + 81920);
    int*   flag   = (int*)(ws + 82432);
    u16*   Bfrag  = (u16*)(ws + 82496);
    u16*   Afrag  = (u16*)(ws + 90688);
    int*   srcA   = (int*)(ws + 131072);
    int*   dstA   = (int*)(ws + 2691072);
    int*   counts = (int*)(ws + 5251072);
    int*   cursor = (int*)(ws + 5651072);
    int*   bsum   = (int*)(ws + 6051072);
    int*   boff   = (int*)(ws + 6051584);
    int*   offs   = (int*)(ws + 6052096);
    int*   perm   = (int*)(ws + 6452096);
    int*   src_s  = (int*)(ws + 9012096);
    int*   dst_s  = (int*)(ws + 11572096);
    u16*   n2b    = (u16*)(ws + 14132096);
    float* agg    = (float*)(ws + 39732096);

    k_fold<<<81, 256, 0, stream>>>(Wx, bx, We, be, Wm, bm, A, B, c);
    k_bfrag<<<16, 256, 0, stream>>>(B, Bfrag);
    k_afrag<<<64, 256, 0, stream>>>(A, Afrag);
    k_detect<<<1, 64, 0, stream>>>((const int*)ei, flag);
    k_zero<<<196, 256, 0, stream>>>((float4*)counts, 50000);      // counts+cursor
    k_zero<<<2048, 256, 0, stream>>>((float4*)agg, N_NODES * D_O / 4);
    k_extract_hist<<<2500, 256, 0, stream>>>(ei, flag, srcA, dstA, counts);
    k_scan_a<<<NB_SCAN, 256, 0, stream>>>(counts, bsum);
    k_scan_b<<<1, 64, 0, stream>>>(bsum, boff);
    k_scan_c<<<NB_SCAN, 256, 0, stream>>>(counts, boff, offs);
    k_scatter<<<2500, 256, 0, stream>>>(dstA, srcA, offs, cursor, perm, src_s, dst_s);
    k_node<<<(N_NODES + XNS - 1) / XNS, 256, 0, stream>>>(x, Afrag, c, n2b);
    k_edge_mlp<<<NBLK_E, 256, 0, stream>>>(ea, perm, src_s, dst_s, Bfrag, n2b, agg);
    k_final<<<2048, 256, 0, stream>>>(agg, beta, (float4*)d_out);
}

// Round 10
// 207.764 us; speedup vs baseline: 6.8730x; 1.1067x over previous
//
#include <hip/hip_runtime.h>
#include <hip/hip_bf16.h>

#define N_NODES 100000
#define N_EDGES 640000
#define D_EE 32
#define D_O  128
#define SCAN_CHUNK 1024
#define NB_SCAN ((N_NODES + SCAN_CHUNK - 1) / SCAN_CHUNK)  // 98
#define EPB 128                       // edges per k_edge_mlp block
#define NBLK_E (N_EDGES / EPB)        // 5000
#define EAS 40                        // ea_s row stride in bf16 (80B, 16B-aligned)
#define MSS 130                       // msg_s row stride in bf16
#define XNS 64                        // nodes per k_node block
#define XRS 136                       // x_s row stride in bf16 (272B, 16B-aligned)

typedef unsigned short u16;
typedef unsigned int u32;
typedef unsigned char u8;
typedef short bf16x8 __attribute__((ext_vector_type(8)));
typedef float f32x4 __attribute__((ext_vector_type(4)));

// ---------- helpers ----------
__device__ __forceinline__ u16 f2bf(float f) {
    u32 b = __float_as_uint(f);
    return (u16)((b + 0x7FFFu + ((b >> 16) & 1u)) >> 16);  // RNE
}
__device__ __forceinline__ float bf2f(u16 u) {
    return __uint_as_float((u32)u << 16);
}
// int64 little-endian node ids < 2^31 => every odd int32 word is 0.
__device__ __forceinline__ int detect32(const int* __restrict__ ei) {
    int o = 0;
#pragma unroll
    for (int i = 1; i < 64; i += 2) o |= ei[i];
    return o != 0;  // 1 => int32, 0 => int64
}

// ---------- K0: fold weights -> fragment-packed bf16 + bias c ----------
// A[i][j]=sum_k Wx[i][k]*Wm[k][j] -> Afrag[ks][ct][lane][jj] (i=ks*32+l4*8+jj, j=ct*16+l15)
// B[i][j]=sum_k We[i][k]*Wm[128+k][j] -> Bfrag[ct][lane][jj]   (i=l4*8+jj)
// c[j]=bm[j]+sum_k bx[k]*Wm[k][j]+sum_k be[k]*Wm[128+k][j]
__global__ __launch_bounds__(256) void k_fold(
    const float* __restrict__ Wx, const float* __restrict__ bx,
    const float* __restrict__ We, const float* __restrict__ be,
    const float* __restrict__ Wm, const float* __restrict__ bm,
    u16* __restrict__ Afrag, u16* __restrict__ Bfrag, float* __restrict__ c) {
    int idx = blockIdx.x * 256 + threadIdx.x;
    if (idx < 16384) {
        int i = idx >> 7, j = idx & 127;
        float s = 0.f;
        for (int k = 0; k < 128; ++k) s = fmaf(Wx[i * 128 + k], Wm[k * 128 + j], s);
        int ks = i >> 5, r = i & 31, l4 = r >> 3, jj = r & 7;
        int ct = j >> 4, l15 = j & 15;
        Afrag[(ks * 8 + ct) * 512 + (l4 * 16 + l15) * 8 + jj] = f2bf(s);
    } else if (idx < 16384 + 4096) {
        int t = idx - 16384;
        int i = t >> 7, j = t & 127;
        float s = 0.f;
        for (int k = 0; k < 128; ++k) s = fmaf(We[i * 128 + k], Wm[(128 + k) * 128 + j], s);
        int l4 = i >> 3, jj = i & 7, ct = j >> 4, l15 = j & 15;
        Bfrag[ct * 512 + (l4 * 16 + l15) * 8 + jj] = f2bf(s);
    } else if (idx < 16384 + 4096 + 128) {
        int j = idx - 20480;
        float s = bm[j];
        for (int k = 0; k < 128; ++k) s = fmaf(bx[k], Wm[k * 128 + j], s);
        for (int k = 0; k < 128; ++k) s = fmaf(be[k], Wm[(128 + k) * 128 + j], s);
        c[j] = s;
    }
}

// ---------- zero (float4-wide) ----------
__global__ __launch_bounds__(256) void k_zero(float4* __restrict__ p, int n4) {
    int i = blockIdx.x * 256 + threadIdx.x;
    int stride = gridDim.x * 256;
    float4 z = make_float4(0.f, 0.f, 0.f, 0.f);
    for (; i < n4; i += stride) p[i] = z;
}

// ---------- histogram of dst (detect inlined) ----------
__global__ __launch_bounds__(256) void k_hist(
    const void* __restrict__ ei_raw, int* __restrict__ counts) {
    int e = blockIdx.x * 256 + threadIdx.x;
    if (e >= N_EDGES) return;
    int dst;
    if (detect32((const int*)ei_raw)) {
        dst = ((const int*)ei_raw)[N_EDGES + e];
    } else {
        dst = (int)((const long long*)ei_raw)[N_EDGES + e];
    }
    atomicAdd(&counts[dst], 1);
}

// ---------- scan A ----------
__global__ __launch_bounds__(256) void k_scan_a(
    const int* __restrict__ counts, int* __restrict__ bsum) {
    __shared__ int L[256];
    int b = blockIdx.x, t = threadIdx.x;
    int base = b * SCAN_CHUNK + t * 4;
    int s = 0;
#pragma unroll
    for (int r = 0; r < 4; ++r) {
        int i = base + r;
        if (i < N_NODES) s += counts[i];
    }
    L[t] = s;
    __syncthreads();
    for (int h = 128; h > 0; h >>= 1) {
        if (t < h) L[t] += L[t + h];
        __syncthreads();
    }
    if (t == 0) bsum[b] = L[0];
}

// ---------- scan B ----------
__global__ void k_scan_b(const int* __restrict__ bsum, int* __restrict__ boff) {
    if (threadIdx.x == 0 && blockIdx.x == 0) {
        int run = 0;
        for (int i = 0; i < NB_SCAN; ++i) { boff[i] = run; run += bsum[i]; }
    }
}

// ---------- scan C ----------
__global__ __launch_bounds__(256) void k_scan_c(
    const int* __restrict__ counts, const int* __restrict__ boff,
    int* __restrict__ offsets) {
    __shared__ int L[256];
    int b = blockIdx.x, t = threadIdx.x;
    int base = b * SCAN_CHUNK + t * 4;
    int c0 = 0, c1 = 0, c2 = 0, c3 = 0;
    if (base + 0 < N_NODES) c0 = counts[base + 0];
    if (base + 1 < N_NODES) c1 = counts[base + 1];
    if (base + 2 < N_NODES) c2 = counts[base + 2];
    if (base + 3 < N_NODES) c3 = counts[base + 3];
    L[t] = c0 + c1 + c2 + c3;
    __syncthreads();
    if (t == 0) {
        int run = 0;
        for (int i = 0; i < 256; ++i) { int tmp = L[i]; L[i] = run; run += tmp; }
    }
    __syncthreads();
    int o = boff[b] + L[t];
    if (base + 0 < N_NODES) offsets[base + 0] = o;
    if (base + 1 < N_NODES) offsets[base + 1] = o + c0;
    if (base + 2 < N_NODES) offsets[base + 2] = o + c0 + c1;
    if (base + 3 < N_NODES) offsets[base + 3] = o + c0 + c1 + c2;
}

// ---------- scatter: perm/src/dst in dst-sorted order (reads ei direct) ----------
__global__ __launch_bounds__(256) void k_scatter(
    const void* __restrict__ ei_raw, const int* __restrict__ offsets,
    int* __restrict__ cursor, int* __restrict__ perm,
    int* __restrict__ src_s, int* __restrict__ dst_s) {
    int e = blockIdx.x * 256 + threadIdx.x;
    if (e >= N_EDGES) return;
    int src, dst;
    if (detect32((const int*)ei_raw)) {
        src = ((const int*)ei_raw)[e];
        dst = ((const int*)ei_raw)[N_EDGES + e];
    } else {
        src = (int)((const long long*)ei_raw)[e];
        dst = (int)((const long long*)ei_raw)[N_EDGES + e];
    }
    int pos = offsets[dst] + atomicAdd(&cursor[dst], 1);
    perm[pos] = e;
    src_s[pos] = src;
    dst_s[pos] = dst;
}

// ---------- K1: n2 = x @ A + c  via MFMA -> bf16 [100000,128] ----------
// (verified r9) Block = 64 nodes; x -> LDS bf16 stride 136; 4 waves x
// {4 k-steps x 8 col-tiles} MFMA, acc init = c[col]; Afrag L1-hot.
__global__ __launch_bounds__(256, 4) void k_node(
    const float* __restrict__ x, const u16* __restrict__ Afrag,
    const float* __restrict__ c, u16* __restrict__ n2b) {
    __shared__ u16 x_s[XNS * XRS];
    int tid = threadIdx.x;
    int nb = blockIdx.x * XNS;
    {
        int row = tid >> 2, q = tid & 3;
        int node = nb + row;
        u16* wp = &x_s[row * XRS + q * 32];
        if (node < N_NODES) {
            const float4* src = (const float4*)(x + (size_t)node * 128 + q * 32);
#pragma unroll
            for (int i = 0; i < 8; ++i) {
                float4 v = src[i];
                *(ushort4*)(wp + i * 4) =
                    make_ushort4(f2bf(v.x), f2bf(v.y), f2bf(v.z), f2bf(v.w));
            }
        } else {
#pragma unroll
            for (int i = 0; i < 8; ++i)
                *(ushort4*)(wp + i * 4) = make_ushort4(0, 0, 0, 0);
        }
    }
    int lane = tid & 63, wv = tid >> 6;
    int l15 = lane & 15, l4 = lane >> 4;
    f32x4 acc[8];
#pragma unroll
    for (int ct = 0; ct < 8; ++ct) {
        float cv = c[ct * 16 + l15];
        acc[ct] = (f32x4){cv, cv, cv, cv};
    }
    __syncthreads();
    int w16 = wv * 16;
#pragma unroll
    for (int ks = 0; ks < 4; ++ks) {
        bf16x8 af = *(const bf16x8*)(&x_s[(w16 + l15) * XRS + ks * 32 + l4 * 8]);
#pragma unroll
        for (int ct = 0; ct < 8; ++ct) {
            bf16x8 bf = *(const bf16x8*)(Afrag + (size_t)(ks * 8 + ct) * 512 + lane * 8);
            acc[ct] = __builtin_amdgcn_mfma_f32_16x16x32_bf16(af, bf, acc[ct], 0, 0, 0);
        }
    }
    int node0 = nb + w16 + l4 * 4;
#pragma unroll
    for (int ct = 0; ct < 8; ++ct) {
        int col = ct * 16 + l15;
#pragma unroll
        for (int r = 0; r < 4; ++r) {
            int node = node0 + r;
            if (node < N_NODES) n2b[(size_t)node * 128 + col] = f2bf(acc[ct][r]);
        }
    }
}

// ---------- K2: edge MLP via MFMA + union LDS + column sweep ----------
// Block owns 128 sorted edges. sh union: ea staging (10.2KB) then msg
// (33.3KB) -> LDS 34.3KB -> 4 blocks/CU. MFMA + n2b-gather epilogue ->
// msg bf16. Sweep: interior runs -> sigmoid directly to out + flag;
// boundary runs -> atomic agg (finished by k_final).
__global__ __launch_bounds__(256, 4) void k_edge_mlp(
    const float* __restrict__ ea, const int* __restrict__ perm,
    const int* __restrict__ src_s, const int* __restrict__ dst_s,
    const u16* __restrict__ Bfrag, const u16* __restrict__ n2b,
    float* __restrict__ agg, u8* __restrict__ flags,
    const float* __restrict__ beta, float* __restrict__ out) {
    __shared__ union ShMem {
        u16 ea[EPB * EAS];    // 10240 B (staging phase)
        u16 msg[EPB * MSS];   // 33280 B (message phase)
    } sh;
    __shared__ int src_l[EPB];
    __shared__ int dst_l[EPB];
    int tid = threadIdx.x;
    int base = blockIdx.x * EPB;
    if (tid < EPB) {
        src_l[tid] = src_s[base + tid];
        dst_l[tid] = dst_s[base + tid];
    }
    {   // stage ea rows f32 -> bf16: thread t does row t>>1, half t&1
        // (wave wv stages exactly rows wv*32..wv*32+31 = its own MFMA rows)
        int row = tid >> 1, q = tid & 1;
        int p = perm[base + row];
        const float4* s4 = (const float4*)(ea + (size_t)p * 32 + q * 16);
        float4 v0 = s4[0], v1 = s4[1], v2 = s4[2], v3 = s4[3];
        u16* wp = &sh.ea[row * EAS + q * 16];
        *(ushort4*)(wp + 0)  = make_ushort4(f2bf(v0.x), f2bf(v0.y), f2bf(v0.z), f2bf(v0.w));
        *(ushort4*)(wp + 4)  = make_ushort4(f2bf(v1.x), f2bf(v1.y), f2bf(v1.z), f2bf(v1.w));
        *(ushort4*)(wp + 8)  = make_ushort4(f2bf(v2.x), f2bf(v2.y), f2bf(v2.z), f2bf(v2.w));
        *(ushort4*)(wp + 12) = make_ushort4(f2bf(v3.x), f2bf(v3.y), f2bf(v3.z), f2bf(v3.w));
    }
    int lane = tid & 63, wv = tid >> 6;
    int l15 = lane & 15, l4 = lane >> 4;
    bf16x8 bfr[8];
#pragma unroll
    for (int ct = 0; ct < 8; ++ct)
        bfr[ct] = *(const bf16x8*)(Bfrag + ct * 512 + lane * 8);
    float rb = fmaxf(beta[0], 0.f);
    __syncthreads();   // ea + src/dst_l visible
    bf16x8 af0 = *(const bf16x8*)(&sh.ea[(wv * 32 + 0  + l15) * EAS + l4 * 8]);
    bf16x8 af1 = *(const bf16x8*)(&sh.ea[(wv * 32 + 16 + l15) * EAS + l4 * 8]);
    __syncthreads();   // all waves done reading sh.ea -> safe to write sh.msg

#pragma unroll
    for (int et = 0; et < 2; ++et) {
        bf16x8 af = et ? af1 : af0;
        int e0 = wv * 32 + et * 16 + l4 * 4;
        const u16* nr0 = n2b + (size_t)src_l[e0 + 0] * 128;
        const u16* nr1 = n2b + (size_t)src_l[e0 + 1] * 128;
        const u16* nr2 = n2b + (size_t)src_l[e0 + 2] * 128;
        const u16* nr3 = n2b + (size_t)src_l[e0 + 3] * 128;
#pragma unroll
        for (int ct = 0; ct < 8; ++ct) {
            f32x4 acc = {0.f, 0.f, 0.f, 0.f};
            acc = __builtin_amdgcn_mfma_f32_16x16x32_bf16(af, bfr[ct], acc, 0, 0, 0);
            int col = ct * 16 + l15;
            float m0 = acc[0] + bf2f(nr0[col]);
            float m1 = acc[1] + bf2f(nr1[col]);
            float m2 = acc[2] + bf2f(nr2[col]);
            float m3 = acc[3] + bf2f(nr3[col]);
            m0 = m0 > 0.f ? m0 : 0.01f * m0;
            m1 = m1 > 0.f ? m1 : 0.01f * m1;
            m2 = m2 > 0.f ? m2 : 0.01f * m2;
            m3 = m3 > 0.f ? m3 : 0.01f * m3;
            sh.msg[(e0 + 0) * MSS + col] = f2bf(m0);
            sh.msg[(e0 + 1) * MSS + col] = f2bf(m1);
            sh.msg[(e0 + 2) * MSS + col] = f2bf(m2);
            sh.msg[(e0 + 3) * MSS + col] = f2bf(m3);
        }
    }
    __syncthreads();

    int c = tid & 127, h = tid >> 7;
    int ebeg = h * 64, eend = ebeg + 64;
    float acc = 0.f;
    int cur = dst_l[ebeg];
    int nflush = 0;
    for (int e = ebeg; e < eend; ++e) {
        int d = dst_l[e];
        if (d != cur) {
            if (nflush) {   // run strictly inside segment: node complete
                out[(size_t)cur * 128 + c] = rb / (1.f + __expf(-acc));
                if (c == 0) flags[cur] = 1;
            } else {        // touches segment start
                unsafeAtomicAdd(agg + (size_t)cur * 128 + c, acc);
            }
            ++nflush;
            acc = 0.f;
            cur = d;
        }
        acc += bf2f(sh.msg[e * MSS + c]);
    }
    unsafeAtomicAdd(agg + (size_t)cur * 128 + c, acc);  // touches segment end
}

// ---------- K3: finish boundary + zero-degree nodes ----------
__global__ __launch_bounds__(256) void k_final(
    const float* __restrict__ agg, const u8* __restrict__ flags,
    const float* __restrict__ beta, float4* __restrict__ out) {
    float rb = fmaxf(beta[0], 0.f);
    int i = blockIdx.x * 256 + threadIdx.x;
    int stride = gridDim.x * 256;
    const float4* a4 = (const float4*)agg;
    const int n4 = N_NODES * 32;   // 32 float4 per node
    for (; i < n4; i += stride) {
        int node = i >> 5;
        if (flags[node]) continue;   // interior node: out already written
        float4 v = a4[i];
        float4 r;
        r.x = rb / (1.f + __expf(-v.x));
        r.y = rb / (1.f + __expf(-v.y));
        r.z = rb / (1.f + __expf(-v.z));
        r.w = rb / (1.f + __expf(-v.w));
        out[i] = r;
    }
}

// ---------- launch ----------
extern "C" void kernel_launch(void* const* d_in, const int* in_sizes, int n_in,
                              void* d_out, int out_size, void* d_ws, size_t ws_size,
                              hipStream_t stream) {
    const float* x    = (const float*)d_in[0];
    const float* ea   = (const float*)d_in[1];
    const float* Wx   = (const float*)d_in[2];
    const float* bx   = (const float*)d_in[3];
    const float* We   = (const float*)d_in[4];
    const float* be   = (const float*)d_in[5];
    const float* Wm   = (const float*)d_in[6];
    const float* bm   = (const float*)d_in[7];
    const float* beta = (const float*)d_in[8];
    const void*  ei   = d_in[9];

    // ws layout (byte offsets):
    //   c @0 (512), Bfrag @512 (8192), Afrag @8704 (32768) -> 41472
    //   [zero block: counts @41472 (400000), cursor @441472 (400000),
    //    flags @841472 (102400), agg @943872 (51200000)] -> 52143872
    //   bsum @52143872 (512), boff @52144384 (512), offs @52144896 (400000)
    //   perm @52544896, src_s @55104896, dst_s @57664896 (each 2560000)
    //   n2b @60224896 (25600000) -> 85824896
    if (ws_size < (size_t)85824896) return;

    char* ws = (char*)d_ws;
    float* c      = (float*)(ws);
    u16*   Bfrag  = (u16*)(ws + 512);
    u16*   Afrag  = (u16*)(ws + 8704);
    int*   counts = (int*)(ws + 41472);
    int*   cursor = (int*)(ws + 441472);
    u8*    flags  = (u8*)(ws + 841472);
    float* agg    = (float*)(ws + 943872);
    int*   bsum   = (int*)(ws + 52143872);
    int*   boff   = (int*)(ws + 52144384);
    int*   offs   = (int*)(ws + 52144896);
    int*   perm   = (int*)(ws + 52544896);
    int*   src_s  = (int*)(ws + 55104896);
    int*   dst_s  = (int*)(ws + 57664896);
    u16*   n2b    = (u16*)(ws + 60224896);

    k_fold<<<81, 256, 0, stream>>>(Wx, bx, We, be, Wm, bm, Afrag, Bfrag, c);
    // zero counts+cursor+flags+agg (contiguous 52,102,400 B)
    k_zero<<<2048, 256, 0, stream>>>((float4*)(ws + 41472), 3256400);
    k_hist<<<2500, 256, 0, stream>>>(ei, counts);
    k_scan_a<<<NB_SCAN, 256, 0, stream>>>(counts, bsum);
    k_scan_b<<<1, 64, 0, stream>>>(bsum, boff);
    k_scan_c<<<NB_SCAN, 256, 0, stream>>>(counts, boff, offs);
    k_scatter<<<2500, 256, 0, stream>>>(ei, offs, cursor, perm, src_s, dst_s);
    k_node<<<(N_NODES + XNS - 1) / XNS, 256, 0, stream>>>(x, Afrag, c, n2b);
    k_edge_mlp<<<NBLK_E, 256, 0, stream>>>(ea, perm, src_s, dst_s, Bfrag, n2b,
                                           agg, flags, beta, (float*)d_out);
    k_final<<<2048, 256, 0, stream>>>(agg, flags, beta, (float4*)d_out);
}

// Round 11
// 207.341 us; speedup vs baseline: 6.8870x; 1.0020x over previous
//
#include <hip/hip_runtime.h>
#include <hip/hip_bf16.h>

#define N_NODES 100000
#define N_EDGES 640000
#define D_EE 32
#define D_O  128
#define SCAN_CHUNK 1024
#define NB_SCAN ((N_NODES + SCAN_CHUNK - 1) / SCAN_CHUNK)  // 98
#define EPB 128                       // edges per k_edge_mlp block
#define NBLK_E (N_EDGES / EPB)        // 5000
#define EAS 40                        // ea_s row stride in bf16 (80B, 16B-aligned)
#define MSS 130                       // msg_s row stride in bf16
#define XNS 64                        // nodes per k_node block
#define XRS 136                       // x_s row stride in bf16 (272B, 16B-aligned)

typedef unsigned short u16;
typedef unsigned int u32;
typedef unsigned char u8;
typedef short bf16x8 __attribute__((ext_vector_type(8)));
typedef float f32x4 __attribute__((ext_vector_type(4)));

// ---------- helpers ----------
__device__ __forceinline__ u16 f2bf(float f) {
    u32 b = __float_as_uint(f);
    return (u16)((b + 0x7FFFu + ((b >> 16) & 1u)) >> 16);  // RNE
}
__device__ __forceinline__ float bf2f(u16 u) {
    return __uint_as_float((u32)u << 16);
}
// int64 little-endian node ids < 2^31 => every odd int32 word is 0.
__device__ __forceinline__ int detect32(const int* __restrict__ ei) {
    int o = 0;
#pragma unroll
    for (int i = 1; i < 64; i += 2) o |= ei[i];
    return o != 0;  // 1 => int32, 0 => int64
}

// ---------- K0: fold weights -> fragment-packed bf16 + bias c ----------
// A[i][j]=sum_k Wx[i][k]*Wm[k][j] -> Afrag[ks][ct][lane][jj] (i=ks*32+l4*8+jj, j=ct*16+l15)
// B[i][j]=sum_k We[i][k]*Wm[128+k][j] -> Bfrag[ct][lane][jj]   (i=l4*8+jj)
// c[j]=bm[j]+sum_k bx[k]*Wm[k][j]+sum_k be[k]*Wm[128+k][j]
__global__ __launch_bounds__(256) void k_fold(
    const float* __restrict__ Wx, const float* __restrict__ bx,
    const float* __restrict__ We, const float* __restrict__ be,
    const float* __restrict__ Wm, const float* __restrict__ bm,
    u16* __restrict__ Afrag, u16* __restrict__ Bfrag, float* __restrict__ c) {
    int idx = blockIdx.x * 256 + threadIdx.x;
    if (idx < 16384) {
        int i = idx >> 7, j = idx & 127;
        float s = 0.f;
        for (int k = 0; k < 128; ++k) s = fmaf(Wx[i * 128 + k], Wm[k * 128 + j], s);
        int ks = i >> 5, r = i & 31, l4 = r >> 3, jj = r & 7;
        int ct = j >> 4, l15 = j & 15;
        Afrag[(ks * 8 + ct) * 512 + (l4 * 16 + l15) * 8 + jj] = f2bf(s);
    } else if (idx < 16384 + 4096) {
        int t = idx - 16384;
        int i = t >> 7, j = t & 127;
        float s = 0.f;
        for (int k = 0; k < 128; ++k) s = fmaf(We[i * 128 + k], Wm[(128 + k) * 128 + j], s);
        int l4 = i >> 3, jj = i & 7, ct = j >> 4, l15 = j & 15;
        Bfrag[ct * 512 + (l4 * 16 + l15) * 8 + jj] = f2bf(s);
    } else if (idx < 16384 + 4096 + 128) {
        int j = idx - 20480;
        float s = bm[j];
        for (int k = 0; k < 128; ++k) s = fmaf(bx[k], Wm[k * 128 + j], s);
        for (int k = 0; k < 128; ++k) s = fmaf(be[k], Wm[(128 + k) * 128 + j], s);
        c[j] = s;
    }
}

// ---------- zero (float4-wide) ----------
__global__ __launch_bounds__(256) void k_zero(float4* __restrict__ p, int n4) {
    int i = blockIdx.x * 256 + threadIdx.x;
    int stride = gridDim.x * 256;
    float4 z = make_float4(0.f, 0.f, 0.f, 0.f);
    for (; i < n4; i += stride) p[i] = z;
}

// ---------- histogram of dst (detect inlined) ----------
__global__ __launch_bounds__(256) void k_hist(
    const void* __restrict__ ei_raw, int* __restrict__ counts) {
    int e = blockIdx.x * 256 + threadIdx.x;
    if (e >= N_EDGES) return;
    int dst;
    if (detect32((const int*)ei_raw)) {
        dst = ((const int*)ei_raw)[N_EDGES + e];
    } else {
        dst = (int)((const long long*)ei_raw)[N_EDGES + e];
    }
    atomicAdd(&counts[dst], 1);
}

// ---------- scan A ----------
__global__ __launch_bounds__(256) void k_scan_a(
    const int* __restrict__ counts, int* __restrict__ bsum) {
    __shared__ int L[256];
    int b = blockIdx.x, t = threadIdx.x;
    int base = b * SCAN_CHUNK + t * 4;
    int s = 0;
#pragma unroll
    for (int r = 0; r < 4; ++r) {
        int i = base + r;
        if (i < N_NODES) s += counts[i];
    }
    L[t] = s;
    __syncthreads();
    for (int h = 128; h > 0; h >>= 1) {
        if (t < h) L[t] += L[t + h];
        __syncthreads();
    }
    if (t == 0) bsum[b] = L[0];
}

// ---------- scan B ----------
__global__ void k_scan_b(const int* __restrict__ bsum, int* __restrict__ boff) {
    if (threadIdx.x == 0 && blockIdx.x == 0) {
        int run = 0;
        for (int i = 0; i < NB_SCAN; ++i) { boff[i] = run; run += bsum[i]; }
    }
}

// ---------- scan C ----------
__global__ __launch_bounds__(256) void k_scan_c(
    const int* __restrict__ counts, const int* __restrict__ boff,
    int* __restrict__ offsets) {
    __shared__ int L[256];
    int b = blockIdx.x, t = threadIdx.x;
    int base = b * SCAN_CHUNK + t * 4;
    int c0 = 0, c1 = 0, c2 = 0, c3 = 0;
    if (base + 0 < N_NODES) c0 = counts[base + 0];
    if (base + 1 < N_NODES) c1 = counts[base + 1];
    if (base + 2 < N_NODES) c2 = counts[base + 2];
    if (base + 3 < N_NODES) c3 = counts[base + 3];
    L[t] = c0 + c1 + c2 + c3;
    __syncthreads();
    if (t == 0) {
        int run = 0;
        for (int i = 0; i < 256; ++i) { int tmp = L[i]; L[i] = run; run += tmp; }
    }
    __syncthreads();
    int o = boff[b] + L[t];
    if (base + 0 < N_NODES) offsets[base + 0] = o;
    if (base + 1 < N_NODES) offsets[base + 1] = o + c0;
    if (base + 2 < N_NODES) offsets[base + 2] = o + c0 + c1;
    if (base + 3 < N_NODES) offsets[base + 3] = o + c0 + c1 + c2;
}

// ---------- scatter: perm/src/dst in dst-sorted order (reads ei direct) ----------
__global__ __launch_bounds__(256) void k_scatter(
    const void* __restrict__ ei_raw, const int* __restrict__ offsets,
    int* __restrict__ cursor, int* __restrict__ perm,
    int* __restrict__ src_s, int* __restrict__ dst_s) {
    int e = blockIdx.x * 256 + threadIdx.x;
    if (e >= N_EDGES) return;
    int src, dst;
    if (detect32((const int*)ei_raw)) {
        src = ((const int*)ei_raw)[e];
        dst = ((const int*)ei_raw)[N_EDGES + e];
    } else {
        src = (int)((const long long*)ei_raw)[e];
        dst = (int)((const long long*)ei_raw)[N_EDGES + e];
    }
    int pos = offsets[dst] + atomicAdd(&cursor[dst], 1);
    perm[pos] = e;
    src_s[pos] = src;
    dst_s[pos] = dst;
}

// ---------- K1: n2 = x @ A + c  via MFMA -> bf16 [100000,128] ----------
// (verified r9) Block = 64 nodes; x -> LDS bf16 stride 136; 4 waves x
// {4 k-steps x 8 col-tiles} MFMA, acc init = c[col]; Afrag L1-hot.
__global__ __launch_bounds__(256, 4) void k_node(
    const float* __restrict__ x, const u16* __restrict__ Afrag,
    const float* __restrict__ c, u16* __restrict__ n2b) {
    __shared__ u16 x_s[XNS * XRS];
    int tid = threadIdx.x;
    int nb = blockIdx.x * XNS;
    {
        int row = tid >> 2, q = tid & 3;
        int node = nb + row;
        u16* wp = &x_s[row * XRS + q * 32];
        if (node < N_NODES) {
            const float4* src = (const float4*)(x + (size_t)node * 128 + q * 32);
#pragma unroll
            for (int i = 0; i < 8; ++i) {
                float4 v = src[i];
                *(ushort4*)(wp + i * 4) =
                    make_ushort4(f2bf(v.x), f2bf(v.y), f2bf(v.z), f2bf(v.w));
            }
        } else {
#pragma unroll
            for (int i = 0; i < 8; ++i)
                *(ushort4*)(wp + i * 4) = make_ushort4(0, 0, 0, 0);
        }
    }
    int lane = tid & 63, wv = tid >> 6;
    int l15 = lane & 15, l4 = lane >> 4;
    f32x4 acc[8];
#pragma unroll
    for (int ct = 0; ct < 8; ++ct) {
        float cv = c[ct * 16 + l15];
        acc[ct] = (f32x4){cv, cv, cv, cv};
    }
    __syncthreads();
    int w16 = wv * 16;
#pragma unroll
    for (int ks = 0; ks < 4; ++ks) {
        bf16x8 af = *(const bf16x8*)(&x_s[(w16 + l15) * XRS + ks * 32 + l4 * 8]);
#pragma unroll
        for (int ct = 0; ct < 8; ++ct) {
            bf16x8 bf = *(const bf16x8*)(Afrag + (size_t)(ks * 8 + ct) * 512 + lane * 8);
            acc[ct] = __builtin_amdgcn_mfma_f32_16x16x32_bf16(af, bf, acc[ct], 0, 0, 0);
        }
    }
    int node0 = nb + w16 + l4 * 4;
#pragma unroll
    for (int ct = 0; ct < 8; ++ct) {
        int col = ct * 16 + l15;
#pragma unroll
        for (int r = 0; r < 4; ++r) {
            int node = node0 + r;
            if (node < N_NODES) n2b[(size_t)node * 128 + col] = f2bf(acc[ct][r]);
        }
    }
}

// ---------- K2: edge MLP via MFMA + union LDS + column sweep ----------
// Block owns 128 sorted edges. sh union: ea staging then msg -> 34.3KB ->
// 4 blocks/CU. ALL 64 n2b gather loads batched into registers before the
// second barrier (one amortized L3 round-trip instead of ~16 serial).
// Sweep: interior runs -> sigmoid directly to out + flag; boundary runs ->
// atomic agg (finished by k_final).
__global__ __launch_bounds__(256, 4) void k_edge_mlp(
    const float* __restrict__ ea, const int* __restrict__ perm,
    const int* __restrict__ src_s, const int* __restrict__ dst_s,
    const u16* __restrict__ Bfrag, const u16* __restrict__ n2b,
    float* __restrict__ agg, u8* __restrict__ flags,
    const float* __restrict__ beta, float* __restrict__ out) {
    __shared__ union ShMem {
        u16 ea[EPB * EAS];    // 10240 B (staging phase)
        u16 msg[EPB * MSS];   // 33280 B (message phase)
    } sh;
    __shared__ int src_l[EPB];
    __shared__ int dst_l[EPB];
    int tid = threadIdx.x;
    int base = blockIdx.x * EPB;
    if (tid < EPB) {
        src_l[tid] = src_s[base + tid];
        dst_l[tid] = dst_s[base + tid];
    }
    {   // stage ea rows f32 -> bf16: thread t does row t>>1, half t&1
        int row = tid >> 1, q = tid & 1;
        int p = perm[base + row];
        const float4* s4 = (const float4*)(ea + (size_t)p * 32 + q * 16);
        float4 v0 = s4[0], v1 = s4[1], v2 = s4[2], v3 = s4[3];
        u16* wp = &sh.ea[row * EAS + q * 16];
        *(ushort4*)(wp + 0)  = make_ushort4(f2bf(v0.x), f2bf(v0.y), f2bf(v0.z), f2bf(v0.w));
        *(ushort4*)(wp + 4)  = make_ushort4(f2bf(v1.x), f2bf(v1.y), f2bf(v1.z), f2bf(v1.w));
        *(ushort4*)(wp + 8)  = make_ushort4(f2bf(v2.x), f2bf(v2.y), f2bf(v2.z), f2bf(v2.w));
        *(ushort4*)(wp + 12) = make_ushort4(f2bf(v3.x), f2bf(v3.y), f2bf(v3.z), f2bf(v3.w));
    }
    int lane = tid & 63, wv = tid >> 6;
    int l15 = lane & 15, l4 = lane >> 4;
    bf16x8 bfr[8];
#pragma unroll
    for (int ct = 0; ct < 8; ++ct)
        bfr[ct] = *(const bf16x8*)(Bfrag + ct * 512 + lane * 8);
    float rb = fmaxf(beta[0], 0.f);
    __syncthreads();   // ea + src/dst_l visible
    bf16x8 af0 = *(const bf16x8*)(&sh.ea[(wv * 32 + 0  + l15) * EAS + l4 * 8]);
    bf16x8 af1 = *(const bf16x8*)(&sh.ea[(wv * 32 + 16 + l15) * EAS + l4 * 8]);
    // ---- batched n2b gather: all 64 scalar loads issue before the MFMAs ----
    u16 nv0[8][4], nv1[8][4];   // [ct][r] for et=0,1 — fully static indexing
#pragma unroll
    for (int r = 0; r < 4; ++r) {
        const u16* nr = n2b + (size_t)src_l[wv * 32 + 0 * 16 + l4 * 4 + r] * 128 + l15;
#pragma unroll
        for (int ct = 0; ct < 8; ++ct) nv0[ct][r] = nr[ct * 16];
    }
#pragma unroll
    for (int r = 0; r < 4; ++r) {
        const u16* nr = n2b + (size_t)src_l[wv * 32 + 1 * 16 + l4 * 4 + r] * 128 + l15;
#pragma unroll
        for (int ct = 0; ct < 8; ++ct) nv1[ct][r] = nr[ct * 16];
    }
    __syncthreads();   // all waves done reading sh.ea -> safe to write sh.msg

#pragma unroll
    for (int et = 0; et < 2; ++et) {
        bf16x8 af = et ? af1 : af0;
        int e0 = wv * 32 + et * 16 + l4 * 4;
#pragma unroll
        for (int ct = 0; ct < 8; ++ct) {
            f32x4 acc = {0.f, 0.f, 0.f, 0.f};
            acc = __builtin_amdgcn_mfma_f32_16x16x32_bf16(af, bfr[ct], acc, 0, 0, 0);
            int col = ct * 16 + l15;
            float m0 = acc[0] + bf2f(et ? nv1[ct][0] : nv0[ct][0]);
            float m1 = acc[1] + bf2f(et ? nv1[ct][1] : nv0[ct][1]);
            float m2 = acc[2] + bf2f(et ? nv1[ct][2] : nv0[ct][2]);
            float m3 = acc[3] + bf2f(et ? nv1[ct][3] : nv0[ct][3]);
            m0 = m0 > 0.f ? m0 : 0.01f * m0;
            m1 = m1 > 0.f ? m1 : 0.01f * m1;
            m2 = m2 > 0.f ? m2 : 0.01f * m2;
            m3 = m3 > 0.f ? m3 : 0.01f * m3;
            sh.msg[(e0 + 0) * MSS + col] = f2bf(m0);
            sh.msg[(e0 + 1) * MSS + col] = f2bf(m1);
            sh.msg[(e0 + 2) * MSS + col] = f2bf(m2);
            sh.msg[(e0 + 3) * MSS + col] = f2bf(m3);
        }
    }
    __syncthreads();

    int c = tid & 127, h = tid >> 7;
    int ebeg = h * 64, eend = ebeg + 64;
    float acc = 0.f;
    int cur = dst_l[ebeg];
    int nflush = 0;
    for (int e = ebeg; e < eend; ++e) {
        int d = dst_l[e];
        if (d != cur) {
            if (nflush) {   // run strictly inside segment: node complete
                out[(size_t)cur * 128 + c] = rb / (1.f + __expf(-acc));
                if (c == 0) flags[cur] = 1;
            } else {        // touches segment start
                unsafeAtomicAdd(agg + (size_t)cur * 128 + c, acc);
            }
            ++nflush;
            acc = 0.f;
            cur = d;
        }
        acc += bf2f(sh.msg[e * MSS + c]);
    }
    unsafeAtomicAdd(agg + (size_t)cur * 128 + c, acc);  // touches segment end
}

// ---------- K3: finish boundary + zero-degree nodes ----------
__global__ __launch_bounds__(256) void k_final(
    const float* __restrict__ agg, const u8* __restrict__ flags,
    const float* __restrict__ beta, float4* __restrict__ out) {
    float rb = fmaxf(beta[0], 0.f);
    int i = blockIdx.x * 256 + threadIdx.x;
    int stride = gridDim.x * 256;
    const float4* a4 = (const float4*)agg;
    const int n4 = N_NODES * 32;   // 32 float4 per node
    for (; i < n4; i += stride) {
        int node = i >> 5;
        if (flags[node]) continue;   // interior node: out already written
        float4 v = a4[i];
        float4 r;
        r.x = rb / (1.f + __expf(-v.x));
        r.y = rb / (1.f + __expf(-v.y));
        r.z = rb / (1.f + __expf(-v.z));
        r.w = rb / (1.f + __expf(-v.w));
        out[i] = r;
    }
}

// ---------- launch ----------
extern "C" void kernel_launch(void* const* d_in, const int* in_sizes, int n_in,
                              void* d_out, int out_size, void* d_ws, size_t ws_size,
                              hipStream_t stream) {
    const float* x    = (const float*)d_in[0];
    const float* ea   = (const float*)d_in[1];
    const float* Wx   = (const float*)d_in[2];
    const float* bx   = (const float*)d_in[3];
    const float* We   = (const float*)d_in[4];
    const float* be   = (const float*)d_in[5];
    const float* Wm   = (const float*)d_in[6];
    const float* bm   = (const float*)d_in[7];
    const float* beta = (const float*)d_in[8];
    const void*  ei   = d_in[9];

    // ws layout (byte offsets):
    //   c @0 (512), Bfrag @512 (8192), Afrag @8704 (32768) -> 41472
    //   [zero block: counts @41472 (400000), cursor @441472 (400000),
    //    flags @841472 (102400), agg @943872 (51200000)] -> 52143872
    //   bsum @52143872 (512), boff @52144384 (512), offs @52144896 (400000)
    //   perm @52544896, src_s @55104896, dst_s @57664896 (each 2560000)
    //   n2b @60224896 (25600000) -> 85824896
    if (ws_size < (size_t)85824896) return;

    char* ws = (char*)d_ws;
    float* c      = (float*)(ws);
    u16*   Bfrag  = (u16*)(ws + 512);
    u16*   Afrag  = (u16*)(ws + 8704);
    int*   counts = (int*)(ws + 41472);
    int*   cursor = (int*)(ws + 441472);
    u8*    flags  = (u8*)(ws + 841472);
    float* agg    = (float*)(ws + 943872);
    int*   bsum   = (int*)(ws + 52143872);
    int*   boff   = (int*)(ws + 52144384);
    int*   offs   = (int*)(ws + 52144896);
    int*   perm   = (int*)(ws + 52544896);
    int*   src_s  = (int*)(ws + 55104896);
    int*   dst_s  = (int*)(ws + 57664896);
    u16*   n2b    = (u16*)(ws + 60224896);

    k_fold<<<81, 256, 0, stream>>>(Wx, bx, We, be, Wm, bm, Afrag, Bfrag, c);
    // zero counts+cursor+flags+agg (contiguous 52,102,400 B)
    k_zero<<<2048, 256, 0, stream>>>((float4*)(ws + 41472), 3256400);
    k_hist<<<2500, 256, 0, stream>>>(ei, counts);
    k_scan_a<<<NB_SCAN, 256, 0, stream>>>(counts, bsum);
    k_scan_b<<<1, 64, 0, stream>>>(bsum, boff);
    k_scan_c<<<NB_SCAN, 256, 0, stream>>>(counts, boff, offs);
    k_scatter<<<2500, 256, 0, stream>>>(ei, offs, cursor, perm, src_s, dst_s);
    k_node<<<(N_NODES + XNS - 1) / XNS, 256, 0, stream>>>(x, Afrag, c, n2b);
    k_edge_mlp<<<NBLK_E, 256, 0, stream>>>(ea, perm, src_s, dst_s, Bfrag, n2b,
                                           agg, flags, beta, (float*)d_out);
    k_final<<<2048, 256, 0, stream>>>(agg, flags, beta, (float4*)d_out);
}

// Round 13
// 187.135 us; speedup vs baseline: 7.6307x; 1.1080x over previous
//
#include <hip/hip_runtime.h>
#include <hip/hip_bf16.h>

#define N_NODES 100000
#define N_EDGES 640000
#define D_EE 32
#define D_O  128
#define SCAN_CHUNK 1024
#define NB_SCAN ((N_NODES + SCAN_CHUNK - 1) / SCAN_CHUNK)  // 98
#define EPB 128                       // edges per k_edge_mlp block
#define NBLK_E (N_EDGES / EPB)        // 5000
#define EAS 40                        // ea_s row stride in bf16 (80B, 16B-aligned)
#define MSS 130                       // msg_s row stride in bf16
#define XNS 64                        // nodes per k_node block
#define XRS 136                       // x_s row stride in bf16 (272B, 16B-aligned)

typedef unsigned short u16;
typedef unsigned int u32;
typedef unsigned char u8;
typedef short bf16x8 __attribute__((ext_vector_type(8)));
typedef float f32x4 __attribute__((ext_vector_type(4)));

// ---------- helpers (hardware RNE bf16 converts; memcpy-safe bit extract) ----------
__device__ __forceinline__ u16 f2bf(float f) {
    __hip_bfloat16 h = __float2bfloat16(f);
    u16 r;
    __builtin_memcpy(&r, &h, 2);
    return r;
}
__device__ __forceinline__ u32 f2bf2(float a, float b) {
    __hip_bfloat162 h = __float22bfloat162_rn(make_float2(a, b));
    u32 r;
    __builtin_memcpy(&r, &h, 4);
    return r;
}
__device__ __forceinline__ float bf2f(u16 u) {
    return __uint_as_float((u32)u << 16);
}
// int64 little-endian node ids < 2^31 => every odd int32 word is 0.
__device__ __forceinline__ int detect32(const int* __restrict__ ei) {
    int o = 0;
#pragma unroll
    for (int i = 1; i < 64; i += 2) o |= ei[i];
    return o != 0;  // 1 => int32, 0 => int64
}

// ---------- K0: fold weights -> fragment-packed bf16 + bias c ----------
__global__ __launch_bounds__(256) void k_fold(
    const float* __restrict__ Wx, const float* __restrict__ bx,
    const float* __restrict__ We, const float* __restrict__ be,
    const float* __restrict__ Wm, const float* __restrict__ bm,
    u16* __restrict__ Afrag, u16* __restrict__ Bfrag, float* __restrict__ c) {
    int idx = blockIdx.x * 256 + threadIdx.x;
    if (idx < 16384) {
        int i = idx >> 7, j = idx & 127;
        float s = 0.f;
        for (int k = 0; k < 128; ++k) s = fmaf(Wx[i * 128 + k], Wm[k * 128 + j], s);
        int ks = i >> 5, r = i & 31, l4 = r >> 3, jj = r & 7;
        int ct = j >> 4, l15 = j & 15;
        Afrag[(ks * 8 + ct) * 512 + (l4 * 16 + l15) * 8 + jj] = f2bf(s);
    } else if (idx < 16384 + 4096) {
        int t = idx - 16384;
        int i = t >> 7, j = t & 127;
        float s = 0.f;
        for (int k = 0; k < 128; ++k) s = fmaf(We[i * 128 + k], Wm[(128 + k) * 128 + j], s);
        int l4 = i >> 3, jj = i & 7, ct = j >> 4, l15 = j & 15;
        Bfrag[ct * 512 + (l4 * 16 + l15) * 8 + jj] = f2bf(s);
    } else if (idx < 16384 + 4096 + 128) {
        int j = idx - 20480;
        float s = bm[j];
        for (int k = 0; k < 128; ++k) s = fmaf(bx[k], Wm[k * 128 + j], s);
        for (int k = 0; k < 128; ++k) s = fmaf(be[k], Wm[(128 + k) * 128 + j], s);
        c[j] = s;
    }
}

// ---------- zero (float4-wide) ----------
__global__ __launch_bounds__(256) void k_zero(float4* __restrict__ p, int n4) {
    int i = blockIdx.x * 256 + threadIdx.x;
    int stride = gridDim.x * 256;
    float4 z = make_float4(0.f, 0.f, 0.f, 0.f);
    for (; i < n4; i += stride) p[i] = z;
}

// ---------- histogram of dst (detect inlined) ----------
__global__ __launch_bounds__(256) void k_hist(
    const void* __restrict__ ei_raw, int* __restrict__ counts) {
    int e = blockIdx.x * 256 + threadIdx.x;
    if (e >= N_EDGES) return;
    int dst;
    if (detect32((const int*)ei_raw)) {
        dst = ((const int*)ei_raw)[N_EDGES + e];
    } else {
        dst = (int)((const long long*)ei_raw)[N_EDGES + e];
    }
    atomicAdd(&counts[dst], 1);
}

// ---------- scan A ----------
__global__ __launch_bounds__(256) void k_scan_a(
    const int* __restrict__ counts, int* __restrict__ bsum) {
    __shared__ int L[256];
    int b = blockIdx.x, t = threadIdx.x;
    int base = b * SCAN_CHUNK + t * 4;
    int s = 0;
#pragma unroll
    for (int r = 0; r < 4; ++r) {
        int i = base + r;
        if (i < N_NODES) s += counts[i];
    }
    L[t] = s;
    __syncthreads();
    for (int h = 128; h > 0; h >>= 1) {
        if (t < h) L[t] += L[t + h];
        __syncthreads();
    }
    if (t == 0) bsum[b] = L[0];
}

// ---------- scan B ----------
__global__ void k_scan_b(const int* __restrict__ bsum, int* __restrict__ boff) {
    if (threadIdx.x == 0 && blockIdx.x == 0) {
        int run = 0;
        for (int i = 0; i < NB_SCAN; ++i) { boff[i] = run; run += bsum[i]; }
    }
}

// ---------- scan C ----------
__global__ __launch_bounds__(256) void k_scan_c(
    const int* __restrict__ counts, const int* __restrict__ boff,
    int* __restrict__ offsets) {
    __shared__ int L[256];
    int b = blockIdx.x, t = threadIdx.x;
    int base = b * SCAN_CHUNK + t * 4;
    int c0 = 0, c1 = 0, c2 = 0, c3 = 0;
    if (base + 0 < N_NODES) c0 = counts[base + 0];
    if (base + 1 < N_NODES) c1 = counts[base + 1];
    if (base + 2 < N_NODES) c2 = counts[base + 2];
    if (base + 3 < N_NODES) c3 = counts[base + 3];
    L[t] = c0 + c1 + c2 + c3;
    __syncthreads();
    if (t == 0) {
        int run = 0;
        for (int i = 0; i < 256; ++i) { int tmp = L[i]; L[i] = run; run += tmp; }
    }
    __syncthreads();
    int o = boff[b] + L[t];
    if (base + 0 < N_NODES) offsets[base + 0] = o;
    if (base + 1 < N_NODES) offsets[base + 1] = o + c0;
    if (base + 2 < N_NODES) offsets[base + 2] = o + c0 + c1;
    if (base + 3 < N_NODES) offsets[base + 3] = o + c0 + c1 + c2;
}

// ---------- scatter: perm/src/dst in dst-sorted order ----------
__global__ __launch_bounds__(256) void k_scatter(
    const void* __restrict__ ei_raw, const int* __restrict__ offsets,
    int* __restrict__ cursor, int* __restrict__ perm,
    int* __restrict__ src_s, int* __restrict__ dst_s) {
    int e = blockIdx.x * 256 + threadIdx.x;
    if (e >= N_EDGES) return;
    int src, dst;
    if (detect32((const int*)ei_raw)) {
        src = ((const int*)ei_raw)[e];
        dst = ((const int*)ei_raw)[N_EDGES + e];
    } else {
        src = (int)((const long long*)ei_raw)[e];
        dst = (int)((const long long*)ei_raw)[N_EDGES + e];
    }
    int pos = offsets[dst] + atomicAdd(&cursor[dst], 1);
    perm[pos] = e;
    src_s[pos] = src;
    dst_s[pos] = dst;
}

// ---------- zero boundary agg rows only ----------
// Sweep halves split chunks at edges {0,63,64,127}; nodes whose runs touch
// those positions receive atomics into agg -> only their rows need zeroing.
__global__ __launch_bounds__(256) void k_zero_bnd(
    const int* __restrict__ dst_s, float* __restrict__ agg) {
    int w = (blockIdx.x * 256 + threadIdx.x) >> 6;
    int lane = threadIdx.x & 63;
    if (w >= NBLK_E) return;
    int d0 = dst_s[w * EPB + 0];
    int d1 = dst_s[w * EPB + 63];
    int d2 = dst_s[w * EPB + 64];
    int d3 = dst_s[w * EPB + 127];
    float* a0 = agg + (size_t)d0 * 128;
    float* a1 = agg + (size_t)d1 * 128;
    float* a2 = agg + (size_t)d2 * 128;
    float* a3 = agg + (size_t)d3 * 128;
    a0[lane] = 0.f; a0[lane + 64] = 0.f;
    a1[lane] = 0.f; a1[lane + 64] = 0.f;
    a2[lane] = 0.f; a2[lane + 64] = 0.f;
    a3[lane] = 0.f; a3[lane + 64] = 0.f;
}

// ---------- K1: n2 = x @ A + c  via MFMA -> bf16 [100000,128] ----------
__global__ __launch_bounds__(256, 4) void k_node(
    const float* __restrict__ x, const u16* __restrict__ Afrag,
    const float* __restrict__ c, u16* __restrict__ n2b) {
    __shared__ u16 x_s[XNS * XRS];
    int tid = threadIdx.x;
    int nb = blockIdx.x * XNS;
    {
        int row = tid >> 2, q = tid & 3;
        int node = nb + row;
        u16* wp = &x_s[row * XRS + q * 32];
        if (node < N_NODES) {
            const float4* src = (const float4*)(x + (size_t)node * 128 + q * 32);
#pragma unroll
            for (int i = 0; i < 8; ++i) {
                float4 v = src[i];
                *(uint2*)(wp + i * 4) =
                    make_uint2(f2bf2(v.x, v.y), f2bf2(v.z, v.w));
            }
        } else {
#pragma unroll
            for (int i = 0; i < 8; ++i)
                *(uint2*)(wp + i * 4) = make_uint2(0u, 0u);
        }
    }
    int lane = tid & 63, wv = tid >> 6;
    int l15 = lane & 15, l4 = lane >> 4;
    f32x4 acc[8];
#pragma unroll
    for (int ct = 0; ct < 8; ++ct) {
        float cv = c[ct * 16 + l15];
        acc[ct] = (f32x4){cv, cv, cv, cv};
    }
    __syncthreads();
    int w16 = wv * 16;
#pragma unroll
    for (int ks = 0; ks < 4; ++ks) {
        bf16x8 af = *(const bf16x8*)(&x_s[(w16 + l15) * XRS + ks * 32 + l4 * 8]);
#pragma unroll
        for (int ct = 0; ct < 8; ++ct) {
            bf16x8 bf = *(const bf16x8*)(Afrag + (size_t)(ks * 8 + ct) * 512 + lane * 8);
            acc[ct] = __builtin_amdgcn_mfma_f32_16x16x32_bf16(af, bf, acc[ct], 0, 0, 0);
        }
    }
    int node0 = nb + w16 + l4 * 4;
#pragma unroll
    for (int ct = 0; ct < 8; ++ct) {
        int col = ct * 16 + l15;
#pragma unroll
        for (int r = 0; r < 4; ++r) {
            int node = node0 + r;
            if (node < N_NODES) n2b[(size_t)node * 128 + col] = f2bf(acc[ct][r]);
        }
    }
}

// ---------- K2: edge MLP via MFMA + union LDS + column sweep ----------
__global__ __launch_bounds__(256, 4) void k_edge_mlp(
    const float* __restrict__ ea, const int* __restrict__ perm,
    const int* __restrict__ src_s, const int* __restrict__ dst_s,
    const u16* __restrict__ Bfrag, const u16* __restrict__ n2b,
    float* __restrict__ agg, u8* __restrict__ flags,
    const float* __restrict__ beta, float* __restrict__ out) {
    __shared__ union ShMem {
        u16 ea[EPB * EAS];    // 10240 B (staging phase)
        u16 msg[EPB * MSS];   // 33280 B (message phase)
    } sh;
    __shared__ int src_l[EPB];
    __shared__ int dst_l[EPB];
    int tid = threadIdx.x;
    int base = blockIdx.x * EPB;
    if (tid < EPB) {
        src_l[tid] = src_s[base + tid];
        dst_l[tid] = dst_s[base + tid];
    }
    {   // stage ea rows f32 -> bf16 (hardware packed cvt)
        int row = tid >> 1, q = tid & 1;
        int p = perm[base + row];
        const float4* s4 = (const float4*)(ea + (size_t)p * 32 + q * 16);
        float4 v0 = s4[0], v1 = s4[1], v2 = s4[2], v3 = s4[3];
        u16* wp = &sh.ea[row * EAS + q * 16];
        *(uint2*)(wp + 0)  = make_uint2(f2bf2(v0.x, v0.y), f2bf2(v0.z, v0.w));
        *(uint2*)(wp + 4)  = make_uint2(f2bf2(v1.x, v1.y), f2bf2(v1.z, v1.w));
        *(uint2*)(wp + 8)  = make_uint2(f2bf2(v2.x, v2.y), f2bf2(v2.z, v2.w));
        *(uint2*)(wp + 12) = make_uint2(f2bf2(v3.x, v3.y), f2bf2(v3.z, v3.w));
    }
    int lane = tid & 63, wv = tid >> 6;
    int l15 = lane & 15, l4 = lane >> 4;
    bf16x8 bfr[8];
#pragma unroll
    for (int ct = 0; ct < 8; ++ct)
        bfr[ct] = *(const bf16x8*)(Bfrag + ct * 512 + lane * 8);
    float rb = fmaxf(beta[0], 0.f);
    __syncthreads();   // ea + src/dst_l visible
    bf16x8 af0 = *(const bf16x8*)(&sh.ea[(wv * 32 + 0  + l15) * EAS + l4 * 8]);
    bf16x8 af1 = *(const bf16x8*)(&sh.ea[(wv * 32 + 16 + l15) * EAS + l4 * 8]);
    // batched n2b gathers (placement proven r11)
    u16 nv0[8][4], nv1[8][4];
#pragma unroll
    for (int r = 0; r < 4; ++r) {
        const u16* nr = n2b + (size_t)src_l[wv * 32 + 0 * 16 + l4 * 4 + r] * 128 + l15;
#pragma unroll
        for (int ct = 0; ct < 8; ++ct) nv0[ct][r] = nr[ct * 16];
    }
#pragma unroll
    for (int r = 0; r < 4; ++r) {
        const u16* nr = n2b + (size_t)src_l[wv * 32 + 1 * 16 + l4 * 4 + r] * 128 + l15;
#pragma unroll
        for (int ct = 0; ct < 8; ++ct) nv1[ct][r] = nr[ct * 16];
    }
    __syncthreads();   // all waves done reading sh.ea -> safe to write sh.msg

#pragma unroll
    for (int et = 0; et < 2; ++et) {
        bf16x8 af = et ? af1 : af0;
        int e0 = wv * 32 + et * 16 + l4 * 4;
#pragma unroll
        for (int ct = 0; ct < 8; ++ct) {
            f32x4 acc = {0.f, 0.f, 0.f, 0.f};
            acc = __builtin_amdgcn_mfma_f32_16x16x32_bf16(af, bfr[ct], acc, 0, 0, 0);
            int col = ct * 16 + l15;
            float m0 = acc[0] + bf2f(et ? nv1[ct][0] : nv0[ct][0]);
            float m1 = acc[1] + bf2f(et ? nv1[ct][1] : nv0[ct][1]);
            float m2 = acc[2] + bf2f(et ? nv1[ct][2] : nv0[ct][2]);
            float m3 = acc[3] + bf2f(et ? nv1[ct][3] : nv0[ct][3]);
            m0 = fmaxf(m0, 0.01f * m0);   // leaky: max(x, 0.01x)
            m1 = fmaxf(m1, 0.01f * m1);
            m2 = fmaxf(m2, 0.01f * m2);
            m3 = fmaxf(m3, 0.01f * m3);
            u32 w01 = f2bf2(m0, m1);
            sh.msg[(e0 + 0) * MSS + col] = (u16)(w01 & 0xffffu);
            sh.msg[(e0 + 1) * MSS + col] = (u16)(w01 >> 16);
            u32 w23 = f2bf2(m2, m3);
            sh.msg[(e0 + 2) * MSS + col] = (u16)(w23 & 0xffffu);
            sh.msg[(e0 + 3) * MSS + col] = (u16)(w23 >> 16);
        }
    }
    __syncthreads();

    int c = tid & 127, h = tid >> 7;
    int ebeg = h * 64, eend = ebeg + 64;
    float acc = 0.f;
    int cur = dst_l[ebeg];
    int nflush = 0;
    for (int e = ebeg; e < eend; ++e) {
        int d = dst_l[e];
        if (d != cur) {
            if (nflush) {   // run strictly inside segment: node complete
                out[(size_t)cur * 128 + c] = rb / (1.f + __expf(-acc));
                if (c == 0) flags[cur] = 1;
            } else {        // touches segment start
                unsafeAtomicAdd(agg + (size_t)cur * 128 + c, acc);
            }
            ++nflush;
            acc = 0.f;
            cur = d;
        }
        acc += bf2f(sh.msg[e * MSS + c]);
    }
    unsafeAtomicAdd(agg + (size_t)cur * 128 + c, acc);  // touches segment end
}

// ---------- K3: finish boundary + zero-degree nodes ----------
__global__ __launch_bounds__(256) void k_final(
    const float* __restrict__ agg, const u8* __restrict__ flags,
    const int* __restrict__ counts, const float* __restrict__ beta,
    float4* __restrict__ out) {
    float rb = fmaxf(beta[0], 0.f);
    float hb = 0.5f * rb;
    int i = blockIdx.x * 256 + threadIdx.x;
    int stride = gridDim.x * 256;
    const float4* a4 = (const float4*)agg;
    const int n4 = N_NODES * 32;   // 32 float4 per node
    for (; i < n4; i += stride) {
        int node = i >> 5;
        if (flags[node]) continue;           // interior: out already written
        if (counts[node] == 0) {             // zero-degree: sigmoid(0)*rb
            out[i] = make_float4(hb, hb, hb, hb);
            continue;
        }
        float4 v = a4[i];
        float4 r;
        r.x = rb / (1.f + __expf(-v.x));
        r.y = rb / (1.f + __expf(-v.y));
        r.z = rb / (1.f + __expf(-v.z));
        r.w = rb / (1.f + __expf(-v.w));
        out[i] = r;
    }
}

// ---------- launch ----------
extern "C" void kernel_launch(void* const* d_in, const int* in_sizes, int n_in,
                              void* d_out, int out_size, void* d_ws, size_t ws_size,
                              hipStream_t stream) {
    const float* x    = (const float*)d_in[0];
    const float* ea   = (const float*)d_in[1];
    const float* Wx   = (const float*)d_in[2];
    const float* bx   = (const float*)d_in[3];
    const float* We   = (const float*)d_in[4];
    const float* be   = (const float*)d_in[5];
    const float* Wm   = (const float*)d_in[6];
    const float* bm   = (const float*)d_in[7];
    const float* beta = (const float*)d_in[8];
    const void*  ei   = d_in[9];

    // ws layout (byte offsets) — unchanged from r10/r11:
    //   c @0 (512), Bfrag @512 (8192), Afrag @8704 (32768) -> 41472
    //   counts @41472 (400000), cursor @441472 (400000),
    //   flags @841472 (102400), agg @943872 (51200000) -> 52143872
    //   bsum @52143872 (512), boff @52144384 (512), offs @52144896 (400000)
    //   perm @52544896, src_s @55104896, dst_s @57664896 (each 2560000)
    //   n2b @60224896 (25600000) -> 85824896
    if (ws_size < (size_t)85824896) return;

    char* ws = (char*)d_ws;
    float* c      = (float*)(ws);
    u16*   Bfrag  = (u16*)(ws + 512);
    u16*   Afrag  = (u16*)(ws + 8704);
    int*   counts = (int*)(ws + 41472);
    int*   cursor = (int*)(ws + 441472);
    u8*    flags  = (u8*)(ws + 841472);
    float* agg    = (float*)(ws + 943872);
    int*   bsum   = (int*)(ws + 52143872);
    int*   boff   = (int*)(ws + 52144384);
    int*   offs   = (int*)(ws + 52144896);
    int*   perm   = (int*)(ws + 52544896);
    int*   src_s  = (int*)(ws + 55104896);
    int*   dst_s  = (int*)(ws + 57664896);
    u16*   n2b    = (u16*)(ws + 60224896);

    k_fold<<<81, 256, 0, stream>>>(Wx, bx, We, be, Wm, bm, Afrag, Bfrag, c);
    // zero counts+cursor+flags only (contiguous 902,400 B = 56,400 float4)
    k_zero<<<256, 256, 0, stream>>>((float4*)(ws + 41472), 56400);
    k_hist<<<2500, 256, 0, stream>>>(ei, counts);
    k_scan_a<<<NB_SCAN, 256, 0, stream>>>(counts, bsum);
    k_scan_b<<<1, 64, 0, stream>>>(bsum, boff);
    k_scan_c<<<NB_SCAN, 256, 0, stream>>>(counts, boff, offs);
    k_scatter<<<2500, 256, 0, stream>>>(ei, offs, cursor, perm, src_s, dst_s);
    k_zero_bnd<<<1250, 256, 0, stream>>>(dst_s, agg);
    k_node<<<(N_NODES + XNS - 1) / XNS, 256, 0, stream>>>(x, Afrag, c, n2b);
    k_edge_mlp<<<NBLK_E, 256, 0, stream>>>(ea, perm, src_s, dst_s, Bfrag, n2b,
                                           agg, flags, beta, (float*)d_out);
    k_final<<<2048, 256, 0, stream>>>(agg, flags, counts, beta, (float4*)d_out);
}

// Round 14
// 164.743 us; speedup vs baseline: 8.6679x; 1.1359x over previous
//
#include <hip/hip_runtime.h>
#include <hip/hip_bf16.h>

#define N_NODES 100000
#define N_EDGES 640000
#define D_EE 32
#define D_O  128
#define SCAN_CHUNK 1024
#define NB_SCAN ((N_NODES + SCAN_CHUNK - 1) / SCAN_CHUNK)  // 98
#define EPB 128                       // edges per k_edge_mlp block
#define NBLK_E (N_EDGES / EPB)        // 5000
#define EAS 40                        // ea_s row stride in bf16 (80B, 16B-aligned)
#define MTS 136                       // msg_T col stride in bf16 (272B, 16B-aligned)
#define XNS 64                        // nodes per k_node block
#define XRS 136                       // x_s row stride in bf16 (272B, 16B-aligned)
#define NBLK_N ((N_NODES + XNS - 1) / XNS)   // 1563

typedef unsigned short u16;
typedef unsigned int u32;
typedef unsigned char u8;
typedef short bf16x8 __attribute__((ext_vector_type(8)));
typedef float f32x4 __attribute__((ext_vector_type(4)));

// ---------- helpers (hardware RNE bf16 converts; memcpy-safe bit extract) ----------
__device__ __forceinline__ u16 f2bf(float f) {
    __hip_bfloat16 h = __float2bfloat16(f);
    u16 r;
    __builtin_memcpy(&r, &h, 2);
    return r;
}
__device__ __forceinline__ u32 f2bf2(float a, float b) {
    __hip_bfloat162 h = __float22bfloat162_rn(make_float2(a, b));
    u32 r;
    __builtin_memcpy(&r, &h, 4);
    return r;
}
__device__ __forceinline__ float bf2f(u16 u) {
    return __uint_as_float((u32)u << 16);
}
// int64 little-endian node ids < 2^31 => every odd int32 word is 0.
__device__ __forceinline__ int detect32(const int* __restrict__ ei) {
    int o = 0;
#pragma unroll
    for (int i = 1; i < 64; i += 2) o |= ei[i];
    return o != 0;  // 1 => int32, 0 => int64
}

// ---------- K0: fold weights -> fragment-packed bf16 + bias c; extra blocks zero ----------
__global__ __launch_bounds__(256) void k_fold_zero(
    const float* __restrict__ Wx, const float* __restrict__ bx,
    const float* __restrict__ We, const float* __restrict__ be,
    const float* __restrict__ Wm, const float* __restrict__ bm,
    u16* __restrict__ Afrag, u16* __restrict__ Bfrag, float* __restrict__ c,
    float4* __restrict__ zbase, int zn4) {
    int b = blockIdx.x;
    if (b >= 81) {   // zero phase: blocks 81.. zero counts+cursor+flags
        int i = (b - 81) * 256 + threadIdx.x;
        int stride = (gridDim.x - 81) * 256;
        float4 z = make_float4(0.f, 0.f, 0.f, 0.f);
        for (; i < zn4; i += stride) zbase[i] = z;
        return;
    }
    int idx = b * 256 + threadIdx.x;
    if (idx < 16384) {
        int i = idx >> 7, j = idx & 127;
        float s = 0.f;
        for (int k = 0; k < 128; ++k) s = fmaf(Wx[i * 128 + k], Wm[k * 128 + j], s);
        int ks = i >> 5, r = i & 31, l4 = r >> 3, jj = r & 7;
        int ct = j >> 4, l15 = j & 15;
        Afrag[(ks * 8 + ct) * 512 + (l4 * 16 + l15) * 8 + jj] = f2bf(s);
    } else if (idx < 16384 + 4096) {
        int t = idx - 16384;
        int i = t >> 7, j = t & 127;
        float s = 0.f;
        for (int k = 0; k < 128; ++k) s = fmaf(We[i * 128 + k], Wm[(128 + k) * 128 + j], s);
        int l4 = i >> 3, jj = i & 7, ct = j >> 4, l15 = j & 15;
        Bfrag[ct * 512 + (l4 * 16 + l15) * 8 + jj] = f2bf(s);
    } else if (idx < 16384 + 4096 + 128) {
        int j = idx - 20480;
        float s = bm[j];
        for (int k = 0; k < 128; ++k) s = fmaf(bx[k], Wm[k * 128 + j], s);
        for (int k = 0; k < 128; ++k) s = fmaf(be[k], Wm[(128 + k) * 128 + j], s);
        c[j] = s;
    }
}

// ---------- histogram of dst (detect inlined) ----------
__global__ __launch_bounds__(256) void k_hist(
    const void* __restrict__ ei_raw, int* __restrict__ counts) {
    int e = blockIdx.x * 256 + threadIdx.x;
    if (e >= N_EDGES) return;
    int dst;
    if (detect32((const int*)ei_raw)) {
        dst = ((const int*)ei_raw)[N_EDGES + e];
    } else {
        dst = (int)((const long long*)ei_raw)[N_EDGES + e];
    }
    atomicAdd(&counts[dst], 1);
}

// ---------- scan A: per-1024-chunk sums ----------
__global__ __launch_bounds__(256) void k_scan_a(
    const int* __restrict__ counts, int* __restrict__ bsum) {
    __shared__ int L[256];
    int b = blockIdx.x, t = threadIdx.x;
    int base = b * SCAN_CHUNK + t * 4;
    int s = 0;
#pragma unroll
    for (int r = 0; r < 4; ++r) {
        int i = base + r;
        if (i < N_NODES) s += counts[i];
    }
    L[t] = s;
    __syncthreads();
    for (int h = 128; h > 0; h >>= 1) {
        if (t < h) L[t] += L[t + h];
        __syncthreads();
    }
    if (t == 0) bsum[b] = L[0];
}

// ---------- scan C (absorbs scan B): final exclusive offsets ----------
__global__ __launch_bounds__(256) void k_scan_c(
    const int* __restrict__ counts, const int* __restrict__ bsum,
    int* __restrict__ offsets) {
    __shared__ int L[256];
    __shared__ int BS[128];
    int b = blockIdx.x, t = threadIdx.x;
    if (t < NB_SCAN) BS[t] = bsum[t];
    int base = b * SCAN_CHUNK + t * 4;
    int c0 = 0, c1 = 0, c2 = 0, c3 = 0;
    if (base + 0 < N_NODES) c0 = counts[base + 0];
    if (base + 1 < N_NODES) c1 = counts[base + 1];
    if (base + 2 < N_NODES) c2 = counts[base + 2];
    if (base + 3 < N_NODES) c3 = counts[base + 3];
    L[t] = c0 + c1 + c2 + c3;
    __syncthreads();
    if (t == 0) {
        int run = 0;
        for (int i = 0; i < b; ++i) run += BS[i];   // block offset (was k_scan_b)
        for (int i = 0; i < 256; ++i) { int tmp = L[i]; L[i] = run; run += tmp; }
    }
    __syncthreads();
    int o = L[t];
    if (base + 0 < N_NODES) offsets[base + 0] = o;
    if (base + 1 < N_NODES) offsets[base + 1] = o + c0;
    if (base + 2 < N_NODES) offsets[base + 2] = o + c0 + c1;
    if (base + 3 < N_NODES) offsets[base + 3] = o + c0 + c1 + c2;
}

// ---------- scatter: perm/src/dst in dst-sorted order ----------
__global__ __launch_bounds__(256) void k_scatter(
    const void* __restrict__ ei_raw, const int* __restrict__ offsets,
    int* __restrict__ cursor, int* __restrict__ perm,
    int* __restrict__ src_s, int* __restrict__ dst_s) {
    int e = blockIdx.x * 256 + threadIdx.x;
    if (e >= N_EDGES) return;
    int src, dst;
    if (detect32((const int*)ei_raw)) {
        src = ((const int*)ei_raw)[e];
        dst = ((const int*)ei_raw)[N_EDGES + e];
    } else {
        src = (int)((const long long*)ei_raw)[e];
        dst = (int)((const long long*)ei_raw)[N_EDGES + e];
    }
    int pos = offsets[dst] + atomicAdd(&cursor[dst], 1);
    perm[pos] = e;
    src_s[pos] = src;
    dst_s[pos] = dst;
}

// ---------- K1: n2 = x @ A + c via MFMA; extra blocks zero boundary agg rows ----------
__global__ __launch_bounds__(256, 4) void k_node_bnd(
    const float* __restrict__ x, const u16* __restrict__ Afrag,
    const float* __restrict__ c, u16* __restrict__ n2b,
    const int* __restrict__ dst_s, float* __restrict__ agg) {
    int b = blockIdx.x;
    if (b >= NBLK_N) {   // boundary-zero phase (dst_s ready: scatter ran before)
        int w = (b - NBLK_N) * 4 + (threadIdx.x >> 6);
        int lane = threadIdx.x & 63;
        if (w < NBLK_E) {
            int d0 = dst_s[w * EPB + 0];
            int d1 = dst_s[w * EPB + 63];
            int d2 = dst_s[w * EPB + 64];
            int d3 = dst_s[w * EPB + 127];
            float* a0 = agg + (size_t)d0 * 128;
            float* a1 = agg + (size_t)d1 * 128;
            float* a2 = agg + (size_t)d2 * 128;
            float* a3 = agg + (size_t)d3 * 128;
            a0[lane] = 0.f; a0[lane + 64] = 0.f;
            a1[lane] = 0.f; a1[lane + 64] = 0.f;
            a2[lane] = 0.f; a2[lane + 64] = 0.f;
            a3[lane] = 0.f; a3[lane + 64] = 0.f;
        }
        return;
    }
    __shared__ u16 x_s[XNS * XRS];
    int tid = threadIdx.x;
    int nb = b * XNS;
    {
        int row = tid >> 2, q = tid & 3;
        int node = nb + row;
        u16* wp = &x_s[row * XRS + q * 32];
        if (node < N_NODES) {
            const float4* src = (const float4*)(x + (size_t)node * 128 + q * 32);
#pragma unroll
            for (int i = 0; i < 8; ++i) {
                float4 v = src[i];
                *(uint2*)(wp + i * 4) =
                    make_uint2(f2bf2(v.x, v.y), f2bf2(v.z, v.w));
            }
        } else {
#pragma unroll
            for (int i = 0; i < 8; ++i)
                *(uint2*)(wp + i * 4) = make_uint2(0u, 0u);
        }
    }
    int lane = tid & 63, wv = tid >> 6;
    int l15 = lane & 15, l4 = lane >> 4;
    f32x4 acc[8];
#pragma unroll
    for (int ct = 0; ct < 8; ++ct) {
        float cv = c[ct * 16 + l15];
        acc[ct] = (f32x4){cv, cv, cv, cv};
    }
    __syncthreads();
    int w16 = wv * 16;
#pragma unroll
    for (int ks = 0; ks < 4; ++ks) {
        bf16x8 af = *(const bf16x8*)(&x_s[(w16 + l15) * XRS + ks * 32 + l4 * 8]);
#pragma unroll
        for (int ct = 0; ct < 8; ++ct) {
            bf16x8 bf = *(const bf16x8*)(Afrag + (size_t)(ks * 8 + ct) * 512 + lane * 8);
            acc[ct] = __builtin_amdgcn_mfma_f32_16x16x32_bf16(af, bf, acc[ct], 0, 0, 0);
        }
    }
    int node0 = nb + w16 + l4 * 4;
#pragma unroll
    for (int ct = 0; ct < 8; ++ct) {
        int col = ct * 16 + l15;
#pragma unroll
        for (int r = 0; r < 4; ++r) {
            int node = node0 + r;
            if (node < N_NODES) n2b[(size_t)node * 128 + col] = f2bf(acc[ct][r]);
        }
    }
}

// ---------- K2: edge MLP via MFMA + col-major LDS msg + vectorized sweep ----------
// msg_T[col][MTS=136 edges] bf16: MFMA epilogue writes 4 consecutive edges
// as one uint2; sweep reads 8 edges per ds_read_b128 + dst via int4 pairs.
__global__ __launch_bounds__(256, 4) void k_edge_mlp(
    const float* __restrict__ ea, const int* __restrict__ perm,
    const int* __restrict__ src_s, const int* __restrict__ dst_s,
    const u16* __restrict__ Bfrag, const u16* __restrict__ n2b,
    float* __restrict__ agg, u8* __restrict__ flags,
    const float* __restrict__ beta, float* __restrict__ out) {
    __shared__ union ShMem {
        u16 ea[EPB * EAS];      // 10240 B (staging phase)
        u16 msg[128 * MTS];     // 34816 B (message phase, col-major)
    } sh;
    __shared__ __align__(16) int src_l[EPB];
    __shared__ __align__(16) int dst_l[EPB];
    int tid = threadIdx.x;
    int base = blockIdx.x * EPB;
    if (tid < EPB) {
        src_l[tid] = src_s[base + tid];
        dst_l[tid] = dst_s[base + tid];
    }
    {   // stage ea rows f32 -> bf16 (hardware packed cvt)
        int row = tid >> 1, q = tid & 1;
        int p = perm[base + row];
        const float4* s4 = (const float4*)(ea + (size_t)p * 32 + q * 16);
        float4 v0 = s4[0], v1 = s4[1], v2 = s4[2], v3 = s4[3];
        u16* wp = &sh.ea[row * EAS + q * 16];
        *(uint2*)(wp + 0)  = make_uint2(f2bf2(v0.x, v0.y), f2bf2(v0.z, v0.w));
        *(uint2*)(wp + 4)  = make_uint2(f2bf2(v1.x, v1.y), f2bf2(v1.z, v1.w));
        *(uint2*)(wp + 8)  = make_uint2(f2bf2(v2.x, v2.y), f2bf2(v2.z, v2.w));
        *(uint2*)(wp + 12) = make_uint2(f2bf2(v3.x, v3.y), f2bf2(v3.z, v3.w));
    }
    int lane = tid & 63, wv = tid >> 6;
    int l15 = lane & 15, l4 = lane >> 4;
    bf16x8 bfr[8];
#pragma unroll
    for (int ct = 0; ct < 8; ++ct)
        bfr[ct] = *(const bf16x8*)(Bfrag + ct * 512 + lane * 8);
    float rb = fmaxf(beta[0], 0.f);
    __syncthreads();   // ea + src/dst_l visible
    bf16x8 af0 = *(const bf16x8*)(&sh.ea[(wv * 32 + 0  + l15) * EAS + l4 * 8]);
    bf16x8 af1 = *(const bf16x8*)(&sh.ea[(wv * 32 + 16 + l15) * EAS + l4 * 8]);
    // batched n2b gathers (placement proven r11)
    u16 nv0[8][4], nv1[8][4];
#pragma unroll
    for (int r = 0; r < 4; ++r) {
        const u16* nr = n2b + (size_t)src_l[wv * 32 + 0 * 16 + l4 * 4 + r] * 128 + l15;
#pragma unroll
        for (int ct = 0; ct < 8; ++ct) nv0[ct][r] = nr[ct * 16];
    }
#pragma unroll
    for (int r = 0; r < 4; ++r) {
        const u16* nr = n2b + (size_t)src_l[wv * 32 + 1 * 16 + l4 * 4 + r] * 128 + l15;
#pragma unroll
        for (int ct = 0; ct < 8; ++ct) nv1[ct][r] = nr[ct * 16];
    }
    __syncthreads();   // all waves done reading sh.ea -> safe to write sh.msg

#pragma unroll
    for (int et = 0; et < 2; ++et) {
        bf16x8 af = et ? af1 : af0;
        int e0 = wv * 32 + et * 16 + l4 * 4;
#pragma unroll
        for (int ct = 0; ct < 8; ++ct) {
            f32x4 acc = {0.f, 0.f, 0.f, 0.f};
            acc = __builtin_amdgcn_mfma_f32_16x16x32_bf16(af, bfr[ct], acc, 0, 0, 0);
            int col = ct * 16 + l15;
            float m0 = acc[0] + bf2f(et ? nv1[ct][0] : nv0[ct][0]);
            float m1 = acc[1] + bf2f(et ? nv1[ct][1] : nv0[ct][1]);
            float m2 = acc[2] + bf2f(et ? nv1[ct][2] : nv0[ct][2]);
            float m3 = acc[3] + bf2f(et ? nv1[ct][3] : nv0[ct][3]);
            m0 = fmaxf(m0, 0.01f * m0);   // leaky: max(x, 0.01x)
            m1 = fmaxf(m1, 0.01f * m1);
            m2 = fmaxf(m2, 0.01f * m2);
            m3 = fmaxf(m3, 0.01f * m3);
            u32 w01 = f2bf2(m0, m1);
            u32 w23 = f2bf2(m2, m3);
            *(uint2*)(&sh.msg[col * MTS + e0]) = make_uint2(w01, w23);
        }
    }
    __syncthreads();

    int c = tid & 127, h = tid >> 7;
    const u16* mrow = &sh.msg[c * MTS + h * 64];
    const int4* drow = (const int4*)(dst_l + h * 64);
    float acc = 0.f;
    int cur = dst_l[h * 64];
    int nflush = 0;
#pragma unroll 1
    for (int g = 0; g < 8; ++g) {
        bf16x8 mv = *(const bf16x8*)(mrow + g * 8);
        int4 da = drow[g * 2], db = drow[g * 2 + 1];
        int dd[8] = {da.x, da.y, da.z, da.w, db.x, db.y, db.z, db.w};
#pragma unroll
        for (int j = 0; j < 8; ++j) {
            int d = dd[j];
            if (d != cur) {
                if (nflush) {   // run strictly inside segment: node complete
                    out[(size_t)cur * 128 + c] = rb / (1.f + __expf(-acc));
                    if (c == 0) flags[cur] = 1;
                } else {        // touches segment start
                    unsafeAtomicAdd(agg + (size_t)cur * 128 + c, acc);
                }
                ++nflush;
                acc = 0.f;
                cur = d;
            }
            acc += bf2f((u16)mv[j]);
        }
    }
    unsafeAtomicAdd(agg + (size_t)cur * 128 + c, acc);  // touches segment end
}

// ---------- K3: finish boundary + zero-degree nodes ----------
__global__ __launch_bounds__(256) void k_final(
    const float* __restrict__ agg, const u8* __restrict__ flags,
    const int* __restrict__ counts, const float* __restrict__ beta,
    float4* __restrict__ out) {
    float rb = fmaxf(beta[0], 0.f);
    float hb = 0.5f * rb;
    int i = blockIdx.x * 256 + threadIdx.x;
    int stride = gridDim.x * 256;
    const float4* a4 = (const float4*)agg;
    const int n4 = N_NODES * 32;   // 32 float4 per node
    for (; i < n4; i += stride) {
        int node = i >> 5;
        if (flags[node]) continue;           // interior: out already written
        if (counts[node] == 0) {             // zero-degree: sigmoid(0)*rb
            out[i] = make_float4(hb, hb, hb, hb);
            continue;
        }
        float4 v = a4[i];
        float4 r;
        r.x = rb / (1.f + __expf(-v.x));
        r.y = rb / (1.f + __expf(-v.y));
        r.z = rb / (1.f + __expf(-v.z));
        r.w = rb / (1.f + __expf(-v.w));
        out[i] = r;
    }
}

// ---------- launch ----------
extern "C" void kernel_launch(void* const* d_in, const int* in_sizes, int n_in,
                              void* d_out, int out_size, void* d_ws, size_t ws_size,
                              hipStream_t stream) {
    const float* x    = (const float*)d_in[0];
    const float* ea   = (const float*)d_in[1];
    const float* Wx   = (const float*)d_in[2];
    const float* bx   = (const float*)d_in[3];
    const float* We   = (const float*)d_in[4];
    const float* be   = (const float*)d_in[5];
    const float* Wm   = (const float*)d_in[6];
    const float* bm   = (const float*)d_in[7];
    const float* beta = (const float*)d_in[8];
    const void*  ei   = d_in[9];

    // ws layout (byte offsets) — unchanged from r10-r13:
    //   c @0 (512), Bfrag @512 (8192), Afrag @8704 (32768) -> 41472
    //   counts @41472 (400000), cursor @441472 (400000),
    //   flags @841472 (102400), agg @943872 (51200000) -> 52143872
    //   bsum @52143872 (512), boff @52144384 (512), offs @52144896 (400000)
    //   perm @52544896, src_s @55104896, dst_s @57664896 (each 2560000)
    //   n2b @60224896 (25600000) -> 85824896
    if (ws_size < (size_t)85824896) return;

    char* ws = (char*)d_ws;
    float* c      = (float*)(ws);
    u16*   Bfrag  = (u16*)(ws + 512);
    u16*   Afrag  = (u16*)(ws + 8704);
    int*   counts = (int*)(ws + 41472);
    int*   cursor = (int*)(ws + 441472);
    u8*    flags  = (u8*)(ws + 841472);
    float* agg    = (float*)(ws + 943872);
    int*   bsum   = (int*)(ws + 52143872);
    int*   offs   = (int*)(ws + 52144896);
    int*   perm   = (int*)(ws + 52544896);
    int*   src_s  = (int*)(ws + 55104896);
    int*   dst_s  = (int*)(ws + 57664896);
    u16*   n2b    = (u16*)(ws + 60224896);

    // fold + zero counts/cursor/flags (902,400 B = 56,400 float4)
    k_fold_zero<<<81 + 256, 256, 0, stream>>>(Wx, bx, We, be, Wm, bm,
                                              Afrag, Bfrag, c,
                                              (float4*)(ws + 41472), 56400);
    k_hist<<<2500, 256, 0, stream>>>(ei, counts);
    k_scan_a<<<NB_SCAN, 256, 0, stream>>>(counts, bsum);
    k_scan_c<<<NB_SCAN, 256, 0, stream>>>(counts, bsum, offs);
    k_scatter<<<2500, 256, 0, stream>>>(ei, offs, cursor, perm, src_s, dst_s);
    k_node_bnd<<<NBLK_N + 1250, 256, 0, stream>>>(x, Afrag, c, n2b, dst_s, agg);
    k_edge_mlp<<<NBLK_E, 256, 0, stream>>>(ea, perm, src_s, dst_s, Bfrag, n2b,
                                           agg, flags, beta, (float*)d_out);
    k_final<<<2048, 256, 0, stream>>>(agg, flags, counts, beta, (float4*)d_out);
}